// Round 2
// baseline (848.394 us; speedup 1.0000x reference)
//
#include <hip/hip_runtime.h>
#include <stdint.h>

#define LQ 2048
#define EDIM 1024
#define HN 8
#define DH 128
#define BATCH 4
#define SCALE_LOG2E 0.12753785051263942f  // (1/sqrt(128)) * log2(e) -- folded into Qb

typedef short bf16x8 __attribute__((ext_vector_type(8)));
typedef float f32x4 __attribute__((ext_vector_type(4)));
typedef unsigned short u16;
typedef unsigned short u16x4 __attribute__((ext_vector_type(4)));

__device__ __forceinline__ u16 f2bf(float f) {
  union { float f; uint32_t u; } c; c.f = f;
  uint32_t u = c.u;
  return (u16)((u + 0x7fffu + ((u >> 16) & 1u)) >> 16);
}

__device__ __forceinline__ void async16(const void* g, void* l) {
  __builtin_amdgcn_global_load_lds((const __attribute__((address_space(1))) void*)g,
                                   (__attribute__((address_space(3))) void*)l, 16, 0, 0);
}

// LDS byte address for inline-asm DS ops
__device__ __forceinline__ uint32_t lds_b(const u16* p) {
  return (uint32_t)(uintptr_t)(__attribute__((address_space(3))) const u16*)p;
}
// Issue-only 4x ds_read_b128 (NO drain). Outputs early-clobber; the values are
// NOT valid until a following lgkm_wait_sb<> (counted) executes. DS ops complete
// in order, so lgkmcnt(4) after issuing 4 new reads guarantees the previous 4
// are landed (2-deep pipeline).
__device__ __forceinline__ void ldsr4_issue(bf16x8& d0, bf16x8& d1, bf16x8& d2, bf16x8& d3,
                                            uint32_t a0, uint32_t a1, uint32_t a2, uint32_t a3) {
  asm volatile("ds_read_b128 %0, %4\n\t"
               "ds_read_b128 %1, %5\n\t"
               "ds_read_b128 %2, %6\n\t"
               "ds_read_b128 %3, %7"
               : "=&v"(d0), "=&v"(d1), "=&v"(d2), "=&v"(d3)
               : "v"(a0), "v"(a1), "v"(a2), "v"(a3));
}
// Counted lgkm wait + scheduling fence. The sched_barrier is REQUIRED: hipcc
// hoists register-only MFMA past inline-asm waitcnt ("memory" doesn't order it).
template <int N>
__device__ __forceinline__ void lgkm_wait_sb() {
  asm volatile("s_waitcnt lgkmcnt(%0)" :: "n"(N) : "memory");
  __builtin_amdgcn_sched_barrier(0);
}
// v_cvt_pk_bf16_f32: two f32 -> packed 2xbf16 in one u32 (lo <- first arg).
__device__ __forceinline__ uint32_t cvtpk(float lo, float hi) {
  uint32_t r;
  asm("v_cvt_pk_bf16_f32 %0, %1, %2" : "=v"(r) : "v"(lo), "v"(hi));
  return r;
}
// Issue-only 8x ds_bpermute (NO drain): d{0..3} = {s0,s1}@al,@ah ; d{4..7} for s2,s3.
__device__ __forceinline__ void bperm8_issue(uint32_t& d0, uint32_t& d1, uint32_t& d2, uint32_t& d3,
                                             uint32_t& d4, uint32_t& d5, uint32_t& d6, uint32_t& d7,
                                             uint32_t al, uint32_t ah,
                                             uint32_t s0, uint32_t s1, uint32_t s2, uint32_t s3) {
  asm volatile("ds_bpermute_b32 %0, %8, %10\n\t"
               "ds_bpermute_b32 %1, %8, %11\n\t"
               "ds_bpermute_b32 %2, %9, %10\n\t"
               "ds_bpermute_b32 %3, %9, %11\n\t"
               "ds_bpermute_b32 %4, %8, %12\n\t"
               "ds_bpermute_b32 %5, %8, %13\n\t"
               "ds_bpermute_b32 %6, %9, %12\n\t"
               "ds_bpermute_b32 %7, %9, %13"
               : "=&v"(d0), "=&v"(d1), "=&v"(d2), "=&v"(d3),
                 "=&v"(d4), "=&v"(d5), "=&v"(d6), "=&v"(d7)
               : "v"(al), "v"(ah), "v"(s0), "v"(s1), "v"(s2), "v"(s3));
}

// ---------------- fused prep: cvt inputs + transpose weights ----------------
__global__ __launch_bounds__(256) void prep_kernel(const float* __restrict__ qIn, const float* __restrict__ kvIn,
                                                   const float* __restrict__ w0, const float* __restrict__ w1,
                                                   const float* __restrict__ w2, const float* __restrict__ w3,
                                                   u16* __restrict__ oq, u16* __restrict__ okv,
                                                   u16* __restrict__ o0, u16* __restrict__ o1,
                                                   u16* __restrict__ o2, u16* __restrict__ o3) {
  __shared__ float tile[32][33];
  const int bid = blockIdx.x;
  const int t = threadIdx.x;
  if (bid < 16384) {
    const float* in = (bid >= 8192) ? kvIn : qIn;
    u16* out = (bid >= 8192) ? okv : oq;
    size_t i = (size_t)(bid & 8191) * 256 + t;
    float4 v = ((const float4*)in)[i];
    u16x4 o;
    o.x = f2bf(v.x); o.y = f2bf(v.y); o.z = f2bf(v.z); o.w = f2bf(v.w);
    ((u16x4*)out)[i] = o;
  } else {
    const int idx = bid - 16384;
    const int z = idx >> 10;
    const int rem = idx & 1023;
    const float* in; u16* out;
    switch (z) {
      case 0: in = w0; out = o0; break;
      case 1: in = w1; out = o1; break;
      case 2: in = w2; out = o2; break;
      default: in = w3; out = o3; break;
    }
    const int tx = t & 31, ty = t >> 5;
    const int x0 = (rem & 31) * 32;
    const int y0 = (rem >> 5) * 32;
#pragma unroll
    for (int j = 0; j < 32; j += 8)
      tile[ty + j][tx] = in[(size_t)(y0 + ty + j) * EDIM + x0 + tx];
    __syncthreads();
#pragma unroll
    for (int j = 0; j < 32; j += 8)
      out[(size_t)(x0 + ty + j) * EDIM + (y0 + tx)] = f2bf(tile[tx][ty + j]);
  }
}

// ---------------- BK=64 GEMM core (XOR-swizzled LDS, 128x128 tile) ----------------
struct GemmCore {
  template <typename EpiF>
  static __device__ __forceinline__ void run(const u16* __restrict__ A, const u16* __restrict__ Bt,
                                             int m0, int n0, u16* As, u16* Bs, EpiF epi) {
    const int tid = threadIdx.x;
    const int l = tid & 63;
    const int w = tid >> 6;
    const int wm = (w >> 1) * 64;
    const int wn = (w & 1) * 64;
    const int fm = l & 15;
    const int q4 = l >> 4;
    const int f7 = fm & 7;
    f32x4 acc[4][4] = {};
    for (int k0 = 0; k0 < EDIM; k0 += 64) {
      __syncthreads();
#pragma unroll
      for (int ii = 0; ii < 4; ++ii) {
        const int rloc = w * 32 + ii * 8 + (l >> 3);
        const int cs = (l & 7) ^ (rloc & 7);
        async16(A + (size_t)(m0 + rloc) * EDIM + k0 + cs * 8, &As[(w * 32 + ii * 8) * 64 + l * 8]);
        async16(Bt + (size_t)(n0 + rloc) * EDIM + k0 + cs * 8, &Bs[(w * 32 + ii * 8) * 64 + l * 8]);
      }
      __syncthreads();
#pragma unroll
      for (int ks = 0; ks < 2; ++ks) {
        const int coff = ((ks * 4 + q4) ^ f7) * 8;
        bf16x8 a[4], b[4];
#pragma unroll
        for (int i = 0; i < 4; ++i) a[i] = *(const bf16x8*)&As[(wm + i * 16 + fm) * 64 + coff];
#pragma unroll
        for (int j = 0; j < 4; ++j) b[j] = *(const bf16x8*)&Bs[(wn + j * 16 + fm) * 64 + coff];
#pragma unroll
        for (int i = 0; i < 4; ++i)
#pragma unroll
          for (int j = 0; j < 4; ++j)
            acc[i][j] = __builtin_amdgcn_mfma_f32_16x16x32_bf16(a[i], b[j], acc[i][j], 0, 0, 0);
      }
    }
    const int rr = q4 * 4;
#pragma unroll
    for (int i = 0; i < 4; ++i)
#pragma unroll
      for (int j = 0; j < 4; ++j)
#pragma unroll
        for (int r = 0; r < 4; ++r)
          epi(m0 + wm + i * 16 + rr + r, n0 + wn + j * 16 + fm, acc[i][j][r]);
  }
};

__global__ __launch_bounds__(256) void qkv_gemm(const u16* __restrict__ xq, const u16* __restrict__ xkv,
                                                const u16* __restrict__ WqT, const u16* __restrict__ WkT,
                                                const u16* __restrict__ WvT,
                                                u16* __restrict__ Qb, u16* __restrict__ Kb,
                                                u16* __restrict__ Vt,
                                                const unsigned char* __restrict__ mask,
                                                unsigned char* __restrict__ flags) {
  __shared__ __align__(16) u16 As[128 * 64];
  __shared__ __align__(16) u16 Bs[128 * 64];
  __shared__ int wany[4];
  const int z = blockIdx.z;
  if (z == 3) {
    // mask tile scan: 512 blocks x 16 tiles = 8192 (bh, 128x128-tile) units.
    const int t = threadIdx.x;
    const int unit0 = (blockIdx.x * 8 + blockIdx.y) * 16;
#pragma unroll 1
    for (int u = 0; u < 16; ++u) {
      const int idx = unit0 + u;
      const int bh = idx >> 8;
      const int tile16 = idx & 255;
      const int qt = tile16 >> 4, kt = tile16 & 15;
      const int r = t >> 1;
      const size_t base = ((size_t)bh * LQ + qt * 128 + r) * LQ + kt * 128 + (t & 1) * 64;
      const uint4* p = (const uint4*)(mask + base);
      uint4 a = p[0], c = p[1], d = p[2], e = p[3];
      uint32_t any = a.x | a.y | a.z | a.w | c.x | c.y | c.z | c.w |
                     d.x | d.y | d.z | d.w | e.x | e.y | e.z | e.w;
      int wa = __any(any != 0);
      if ((t & 63) == 0) wany[t >> 6] = wa;
      __syncthreads();
      if (t == 0)
        flags[(size_t)bh * 256 + tile16] = (unsigned char)(wany[0] | wany[1] | wany[2] | wany[3]);
      __syncthreads();  // wany reused next unit
    }
    return;
  }
  if (z == 0) {
    // scale*log2e folded into Q here: saves a v_mul per score in attn softmax
    GemmCore::run(xq, WqT, blockIdx.x * 128, blockIdx.y * 128, As, Bs,
                  [&](int gm, int gn, float v) { Qb[(size_t)gm * EDIM + gn] = f2bf(v * SCALE_LOG2E); });
  } else if (z == 1) {
    GemmCore::run(xkv, WkT, blockIdx.x * 128, blockIdx.y * 128, As, Bs,
                  [&](int gm, int gn, float v) { Kb[(size_t)gm * EDIM + gn] = f2bf(v); });
  } else {
    GemmCore::run(WvT, xkv, blockIdx.y * 128, blockIdx.x * 128, As, Bs,
                  [&](int gm, int gn, float v) {
                    Vt[((size_t)(gn >> 11) * 1024 + gm) * 2048 + (gn & 2047)] = f2bf(v);
                  });
  }
}

__global__ __launch_bounds__(256) void out_gemm(const u16* __restrict__ ctx, const u16* __restrict__ WfcT,
                                                float* __restrict__ out) {
  __shared__ __align__(16) u16 As[128 * 64];
  __shared__ __align__(16) u16 Bs[128 * 64];
  GemmCore::run(ctx, WfcT, blockIdx.x * 128, blockIdx.y * 128, As, Bs,
                [&](int gm, int gn, float v) { out[(size_t)gm * EDIM + gn] = v; });
}

// ---------------- flash attention v5: swapped QK^T, in-register P, pipelined DS ----------------
// v4 -> v5: (1) K-frag reads 2-deep pipelined via issue/lgkmcnt(4) split (reads of
// slot ks+1 overlap MFMAs of slot ks); (2) PV: one combined drain per ns instead of
// 3 serial drains; ns=1 V reads issue under ns=0's 16 MFMAs; (3) s_setprio(1) around
// MFMA clusters (T5, +4-7% on phase-split attn); (4) scale folded into Qb upstream.
__global__ __launch_bounds__(256, 2) void attn_kernel(const u16* __restrict__ Qb, const u16* __restrict__ Kb,
                                                      const u16* __restrict__ Vt,
                                                      const unsigned char* __restrict__ mask,
                                                      const unsigned char* __restrict__ flags,
                                                      u16* __restrict__ ctx) {
  __shared__ __align__(16) u16 Ktile[2][64 * 128];   // [key][d] rows 256B = 16 chunks, XOR-swizzled
  __shared__ __align__(16) u16 Vtile[2][128 * 64];   // [d][key] rows 128B = 8 chunks, XOR-swizzled
  const int tid = threadIdx.x;
  const int l = tid & 63;
  const int w = tid >> 6;
  const int qt = blockIdx.x;
  const int h = blockIdx.y;
  const int b = blockIdx.z;
  const int fm = l & 15;
  const int q4 = l >> 4;
  const int fk = q4 * 8;
  const int f7 = fm & 7;
  const int qbase = qt * 128 + w * 32;
  const int bh = b * HN + h;

  const u16* Kbh = Kb + (size_t)b * LQ * EDIM + h * DH;
  const u16* Vth = Vt + (size_t)bh * DH * LQ;
  const size_t mbase = (size_t)bh * (size_t)LQ * LQ;

  const unsigned char* tf = flags + (size_t)bh * 256 + qt * 16;
  uint32_t fmask = 0;
#pragma unroll
  for (int i = 0; i < 16; ++i) fmask |= (tf[i] ? 1u : 0u) << i;

  // Q fragments (issued before DMA so vmcnt ordering keeps them oldest)
  bf16x8 qf[2][4];
#pragma unroll
  for (int mt = 0; mt < 2; ++mt)
#pragma unroll
    for (int ks = 0; ks < 4; ++ks)
      qf[mt][ks] = *(const bf16x8*)(Qb + (size_t)(b * LQ + qbase + mt * 16 + fm) * EDIM + h * DH + ks * 32 + fk);

  auto stageK = [&](int kt_, int buf) {
#pragma unroll
    for (int ii = 0; ii < 4; ++ii) {
      const int i = w * 4 + ii;
      const int row = i * 4 + (l >> 4);          // key row 0..63
      const int g = (l & 15) ^ (row & 7);        // global chunk fetched into slot l&15
      async16(Kbh + (size_t)(kt_ * 64 + row) * EDIM + g * 8, &Ktile[buf][i * 512 + l * 8]);
    }
  };
  auto stageV = [&](int kt_, int buf) {
#pragma unroll
    for (int ii = 0; ii < 4; ++ii) {
      const int i = w * 4 + ii;
      const int row = i * 8 + (l >> 3);          // d row 0..127
      const int g = (l & 7) ^ (row & 7);
      async16(Vth + (size_t)row * LQ + kt_ * 64 + g * 8, &Vtile[buf][i * 512 + l * 8]);
    }
  };

  stageK(0, 0);
  stageV(0, 0);

  f32x4 o[2][8] = {};
  float lsumv[2] = {0.f, 0.f};
  // bpermute byte addrs: low source lane = (fm, q4'=2(q4&1)), high = +16
  const uint32_t al = (uint32_t)((fm + 16 * (2 * (q4 & 1))) << 2);
  const uint32_t ah = al + 64u;
  const bool sel_hi = (q4 >> 1) != 0;   // kt' = 2ns + (q4>>1)

  for (int it = 0; it < 32; ++it) {
    const int cur = it & 1;
    // one barrier: (a) drains own K/V(it) DMA (issued a full iter ago -> ~free),
    // (b) all waves done reading buffers [1-cur] from iter it-1.
    __syncthreads();
    if (it + 1 < 32) { stageK(it + 1, 1 - cur); stageV(it + 1, 1 - cur); }

    const u16* KT = &Ktile[cur][0];
    const u16* VT = &Vtile[cur][0];

    // ---- St = K Q^T: 2-deep pipelined K-frag reads (issue ks+1 while mul ks)
    f32x4 st[4][2] = {};
    bf16x8 kf[2][4];
    {
      const int slot = q4 ^ f7;                  // ks=0 chunk
      ldsr4_issue(kf[0][0], kf[0][1], kf[0][2], kf[0][3],
                  lds_b(KT + (0 * 16 + fm) * 128 + slot * 8),
                  lds_b(KT + (1 * 16 + fm) * 128 + slot * 8),
                  lds_b(KT + (2 * 16 + fm) * 128 + slot * 8),
                  lds_b(KT + (3 * 16 + fm) * 128 + slot * 8));
    }
#pragma unroll
    for (int ks = 0; ks < 4; ++ks) {
      const int c = ks & 1;
      if (ks + 1 < 4) {
        const int slot = ((ks + 1) * 4 + q4) ^ f7;
        ldsr4_issue(kf[c ^ 1][0], kf[c ^ 1][1], kf[c ^ 1][2], kf[c ^ 1][3],
                    lds_b(KT + (0 * 16 + fm) * 128 + slot * 8),
                    lds_b(KT + (1 * 16 + fm) * 128 + slot * 8),
                    lds_b(KT + (2 * 16 + fm) * 128 + slot * 8),
                    lds_b(KT + (3 * 16 + fm) * 128 + slot * 8));
        lgkm_wait_sb<4>();                       // oldest 4 (slot ks) landed
      } else {
        lgkm_wait_sb<0>();
      }
      __builtin_amdgcn_s_setprio(1);
#pragma unroll
      for (int mt = 0; mt < 2; ++mt) {
        st[0][mt] = __builtin_amdgcn_mfma_f32_16x16x32_bf16(kf[c][0], qf[mt][ks], st[0][mt], 0, 0, 0);
        st[1][mt] = __builtin_amdgcn_mfma_f32_16x16x32_bf16(kf[c][1], qf[mt][ks], st[1][mt], 0, 0, 0);
        st[2][mt] = __builtin_amdgcn_mfma_f32_16x16x32_bf16(kf[c][2], qf[mt][ks], st[2][mt], 0, 0, 0);
        st[3][mt] = __builtin_amdgcn_mfma_f32_16x16x32_bf16(kf[c][3], qf[mt][ks], st[3][mt], 0, 0, 0);
      }
      __builtin_amdgcn_s_setprio(0);
    }

    // ---- softmax (no max-subtraction; masked -> 0; scale pre-folded into Q)
    const int hasMask = (fmask >> (it >> 1)) & 1;
    uint32_t pk[2][4][2];
#pragma unroll
    for (int mt = 0; mt < 2; ++mt) {
      float sum = 0.f;
      if (hasMask) {
        const unsigned char* mrow = mask + mbase + (size_t)(qbase + mt * 16 + fm) * LQ + it * 64 + q4 * 4;
#pragma unroll
        for (int kt = 0; kt < 4; ++kt) {
          const uint32_t mv = *(const uint32_t*)(mrow + kt * 16);
#pragma unroll
          for (int r = 0; r < 4; ++r) {
            float e = ((mv >> (8 * r)) & 0xffu) ? 0.f : exp2f(st[kt][mt][r]);
            st[kt][mt][r] = e;
            sum += e;
          }
        }
      } else {
#pragma unroll
        for (int kt = 0; kt < 4; ++kt)
#pragma unroll
          for (int r = 0; r < 4; ++r) {
            float e = exp2f(st[kt][mt][r]);
            st[kt][mt][r] = e;
            sum += e;
          }
      }
      sum += __shfl_xor(sum, 16);
      sum += __shfl_xor(sum, 32);
      lsumv[mt] += sum;
#pragma unroll
      for (int kt = 0; kt < 4; ++kt) {
        pk[mt][kt][0] = cvtpk(st[kt][mt][0], st[kt][mt][1]);
        pk[mt][kt][1] = cvtpk(st[kt][mt][2], st[kt][mt][3]);
      }
    }

    // ---- O += P V: per ns one combined {bperm x16, V-read x8} issue + single drain
    {
      // ns = 0: issue everything, drain once
      bf16x8 v0, v1, v2, v3, v4, v5, v6, v7;
      const int vs0 = q4 ^ f7;
      ldsr4_issue(v0, v1, v2, v3,
                  lds_b(VT + (0 * 16 + fm) * 64 + vs0 * 8), lds_b(VT + (1 * 16 + fm) * 64 + vs0 * 8),
                  lds_b(VT + (2 * 16 + fm) * 64 + vs0 * 8), lds_b(VT + (3 * 16 + fm) * 64 + vs0 * 8));
      ldsr4_issue(v4, v5, v6, v7,
                  lds_b(VT + (4 * 16 + fm) * 64 + vs0 * 8), lds_b(VT + (5 * 16 + fm) * 64 + vs0 * 8),
                  lds_b(VT + (6 * 16 + fm) * 64 + vs0 * 8), lds_b(VT + (7 * 16 + fm) * 64 + vs0 * 8));
      uint32_t t0, t1, t2, t3, u0, u1, u2, u3;
      uint32_t r0, r1, r2, r3, w0, w1, w2, w3;
      bperm8_issue(t0, t1, t2, t3, u0, u1, u2, u3, al, ah,
                   pk[0][0][0], pk[0][0][1], pk[0][1][0], pk[0][1][1]);
      bperm8_issue(r0, r1, r2, r3, w0, w1, w2, w3, al, ah,
                   pk[1][0][0], pk[1][0][1], pk[1][1][0], pk[1][1][1]);
      lgkm_wait_sb<0>();
      bf16x8 paf0, paf1;
      {
        union { uint32_t u[4]; bf16x8 v; } fb;
        fb.u[0] = sel_hi ? u0 : t0; fb.u[1] = sel_hi ? u1 : t1;
        fb.u[2] = sel_hi ? u2 : t2; fb.u[3] = sel_hi ? u3 : t3;
        paf0 = fb.v;
        fb.u[0] = sel_hi ? w0 : r0; fb.u[1] = sel_hi ? w1 : r1;
        fb.u[2] = sel_hi ? w2 : r2; fb.u[3] = sel_hi ? w3 : r3;
        paf1 = fb.v;
      }
      // ns=1 V reads issue now: they land under the 16 MFMAs below
      bf16x8 x0, x1, x2, x3, x4, x5, x6, x7;
      const int vs1 = (4 + q4) ^ f7;
      ldsr4_issue(x0, x1, x2, x3,
                  lds_b(VT + (0 * 16 + fm) * 64 + vs1 * 8), lds_b(VT + (1 * 16 + fm) * 64 + vs1 * 8),
                  lds_b(VT + (2 * 16 + fm) * 64 + vs1 * 8), lds_b(VT + (3 * 16 + fm) * 64 + vs1 * 8));
      ldsr4_issue(x4, x5, x6, x7,
                  lds_b(VT + (4 * 16 + fm) * 64 + vs1 * 8), lds_b(VT + (5 * 16 + fm) * 64 + vs1 * 8),
                  lds_b(VT + (6 * 16 + fm) * 64 + vs1 * 8), lds_b(VT + (7 * 16 + fm) * 64 + vs1 * 8));
      __builtin_amdgcn_s_setprio(1);
      o[0][0] = __builtin_amdgcn_mfma_f32_16x16x32_bf16(paf0, v0, o[0][0], 0, 0, 0);
      o[1][0] = __builtin_amdgcn_mfma_f32_16x16x32_bf16(paf1, v0, o[1][0], 0, 0, 0);
      o[0][1] = __builtin_amdgcn_mfma_f32_16x16x32_bf16(paf0, v1, o[0][1], 0, 0, 0);
      o[1][1] = __builtin_amdgcn_mfma_f32_16x16x32_bf16(paf1, v1, o[1][1], 0, 0, 0);
      o[0][2] = __builtin_amdgcn_mfma_f32_16x16x32_bf16(paf0, v2, o[0][2], 0, 0, 0);
      o[1][2] = __builtin_amdgcn_mfma_f32_16x16x32_bf16(paf1, v2, o[1][2], 0, 0, 0);
      o[0][3] = __builtin_amdgcn_mfma_f32_16x16x32_bf16(paf0, v3, o[0][3], 0, 0, 0);
      o[1][3] = __builtin_amdgcn_mfma_f32_16x16x32_bf16(paf1, v3, o[1][3], 0, 0, 0);
      o[0][4] = __builtin_amdgcn_mfma_f32_16x16x32_bf16(paf0, v4, o[0][4], 0, 0, 0);
      o[1][4] = __builtin_amdgcn_mfma_f32_16x16x32_bf16(paf1, v4, o[1][4], 0, 0, 0);
      o[0][5] = __builtin_amdgcn_mfma_f32_16x16x32_bf16(paf0, v5, o[0][5], 0, 0, 0);
      o[1][5] = __builtin_amdgcn_mfma_f32_16x16x32_bf16(paf1, v5, o[1][5], 0, 0, 0);
      o[0][6] = __builtin_amdgcn_mfma_f32_16x16x32_bf16(paf0, v6, o[0][6], 0, 0, 0);
      o[1][6] = __builtin_amdgcn_mfma_f32_16x16x32_bf16(paf1, v6, o[1][6], 0, 0, 0);
      o[0][7] = __builtin_amdgcn_mfma_f32_16x16x32_bf16(paf0, v7, o[0][7], 0, 0, 0);
      o[1][7] = __builtin_amdgcn_mfma_f32_16x16x32_bf16(paf1, v7, o[1][7], 0, 0, 0);
      __builtin_amdgcn_s_setprio(0);
      // ns = 1: bperms now, V already in flight/landed
      bperm8_issue(t0, t1, t2, t3, u0, u1, u2, u3, al, ah,
                   pk[0][2][0], pk[0][2][1], pk[0][3][0], pk[0][3][1]);
      bperm8_issue(r0, r1, r2, r3, w0, w1, w2, w3, al, ah,
                   pk[1][2][0], pk[1][2][1], pk[1][3][0], pk[1][3][1]);
      lgkm_wait_sb<0>();
      {
        union { uint32_t u[4]; bf16x8 v; } fb;
        fb.u[0] = sel_hi ? u0 : t0; fb.u[1] = sel_hi ? u1 : t1;
        fb.u[2] = sel_hi ? u2 : t2; fb.u[3] = sel_hi ? u3 : t3;
        paf0 = fb.v;
        fb.u[0] = sel_hi ? w0 : r0; fb.u[1] = sel_hi ? w1 : r1;
        fb.u[2] = sel_hi ? w2 : r2; fb.u[3] = sel_hi ? w3 : r3;
        paf1 = fb.v;
      }
      __builtin_amdgcn_s_setprio(1);
      o[0][0] = __builtin_amdgcn_mfma_f32_16x16x32_bf16(paf0, x0, o[0][0], 0, 0, 0);
      o[1][0] = __builtin_amdgcn_mfma_f32_16x16x32_bf16(paf1, x0, o[1][0], 0, 0, 0);
      o[0][1] = __builtin_amdgcn_mfma_f32_16x16x32_bf16(paf0, x1, o[0][1], 0, 0, 0);
      o[1][1] = __builtin_amdgcn_mfma_f32_16x16x32_bf16(paf1, x1, o[1][1], 0, 0, 0);
      o[0][2] = __builtin_amdgcn_mfma_f32_16x16x32_bf16(paf0, x2, o[0][2], 0, 0, 0);
      o[1][2] = __builtin_amdgcn_mfma_f32_16x16x32_bf16(paf1, x2, o[1][2], 0, 0, 0);
      o[0][3] = __builtin_amdgcn_mfma_f32_16x16x32_bf16(paf0, x3, o[0][3], 0, 0, 0);
      o[1][3] = __builtin_amdgcn_mfma_f32_16x16x32_bf16(paf1, x3, o[1][3], 0, 0, 0);
      o[0][4] = __builtin_amdgcn_mfma_f32_16x16x32_bf16(paf0, x4, o[0][4], 0, 0, 0);
      o[1][4] = __builtin_amdgcn_mfma_f32_16x16x32_bf16(paf1, x4, o[1][4], 0, 0, 0);
      o[0][5] = __builtin_amdgcn_mfma_f32_16x16x32_bf16(paf0, x5, o[0][5], 0, 0, 0);
      o[1][5] = __builtin_amdgcn_mfma_f32_16x16x32_bf16(paf1, x5, o[1][5], 0, 0, 0);
      o[0][6] = __builtin_amdgcn_mfma_f32_16x16x32_bf16(paf0, x6, o[0][6], 0, 0, 0);
      o[1][6] = __builtin_amdgcn_mfma_f32_16x16x32_bf16(paf1, x6, o[1][6], 0, 0, 0);
      o[0][7] = __builtin_amdgcn_mfma_f32_16x16x32_bf16(paf0, x7, o[0][7], 0, 0, 0);
      o[1][7] = __builtin_amdgcn_mfma_f32_16x16x32_bf16(paf1, x7, o[1][7], 0, 0, 0);
      __builtin_amdgcn_s_setprio(0);
    }
  }

  // ---- epilogue: ctx = O / lsum. lsum for q=16mt+(q4*4+r) lives on lane fm'=q4*4+r (q4'=0).
#pragma unroll
  for (int mt = 0; mt < 2; ++mt)
#pragma unroll
    for (int r = 0; r < 4; ++r) {
      float inv = 1.f / __shfl(lsumv[mt], q4 * 4 + r);
      int gq = b * LQ + qbase + mt * 16 + q4 * 4 + r;
#pragma unroll
      for (int dt = 0; dt < 8; ++dt)
        ctx[(size_t)gq * EDIM + h * DH + dt * 16 + fm] = f2bf(o[mt][dt][r] * inv);
    }
}

extern "C" void kernel_launch(void* const* d_in, const int* in_sizes, int n_in,
                              void* d_out, int out_size, void* d_ws, size_t ws_size,
                              hipStream_t stream) {
  const float* qIn = (const float*)d_in[0];
  const float* kvIn = (const float*)d_in[1];
  const unsigned char* mask = (const unsigned char*)d_in[2];
  const float* W_Q = (const float*)d_in[3];
  const float* W_K = (const float*)d_in[4];
  const float* W_V = (const float*)d_in[5];
  const float* W_fc = (const float*)d_in[6];
  float* out = (float*)d_out;

  uint8_t* ws = (uint8_t*)d_ws;
  const size_t MB = 1u << 20;
  u16* xq   = (u16*)(ws);
  u16* xkv  = (u16*)(ws + 16 * MB);
  u16* WqT  = (u16*)(ws + 32 * MB);
  u16* WkT  = (u16*)(ws + 34 * MB);
  u16* WvT  = (u16*)(ws + 36 * MB);
  u16* WfcT = (u16*)(ws + 38 * MB);
  u16* Qb   = (u16*)(ws + 40 * MB);
  u16* Kb   = (u16*)(ws + 56 * MB);
  u16* Vt   = (u16*)(ws + 72 * MB);
  u16* ctx  = (u16*)(ws + 88 * MB);
  unsigned char* flags = (unsigned char*)(ws + 104 * MB);

  prep_kernel<<<20480, 256, 0, stream>>>(qIn, kvIn, W_Q, W_K, W_V, W_fc,
                                         xq, xkv, WqT, WkT, WvT, WfcT);
  qkv_gemm<<<dim3(64, 8, 4), 256, 0, stream>>>(xq, xkv, WqT, WkT, WvT, Qb, Kb, Vt, mask, flags);
  attn_kernel<<<dim3(16, 8, 4), 256, 0, stream>>>(Qb, Kb, Vt, mask, flags, ctx);
  out_gemm<<<dim3(64, 8), 256, 0, stream>>>(ctx, WfcT, out);
}

// Round 4
// 829.246 us; speedup vs baseline: 1.0231x; 1.0231x over previous
//
#include <hip/hip_runtime.h>
#include <stdint.h>

#define LQ 2048
#define EDIM 1024
#define HN 8
#define DH 128
#define BATCH 4
#define SCALE_LOG2E 0.12753785051263942f  // (1/sqrt(128)) * log2(e) -- folded into Qb

typedef short bf16x8 __attribute__((ext_vector_type(8)));
typedef float f32x4 __attribute__((ext_vector_type(4)));
typedef unsigned short u16;
typedef unsigned short u16x4 __attribute__((ext_vector_type(4)));

__device__ __forceinline__ u16 f2bf(float f) {
  union { float f; uint32_t u; } c; c.f = f;
  uint32_t u = c.u;
  return (u16)((u + 0x7fffu + ((u >> 16) & 1u)) >> 16);
}

__device__ __forceinline__ void async16(const void* g, void* l) {
  __builtin_amdgcn_global_load_lds((const __attribute__((address_space(1))) void*)g,
                                   (__attribute__((address_space(3))) void*)l, 16, 0, 0);
}

// LDS byte address for inline-asm DS ops
__device__ __forceinline__ uint32_t lds_b(const u16* p) {
  return (uint32_t)(uintptr_t)(__attribute__((address_space(3))) const u16*)p;
}
// Issue-only 4x ds_read_b128 (NO drain). Outputs early-clobber; values valid only
// after a following counted lgkm wait. DS ops complete in order.
__device__ __forceinline__ void ldsr4_issue(bf16x8& d0, bf16x8& d1, bf16x8& d2, bf16x8& d3,
                                            uint32_t a0, uint32_t a1, uint32_t a2, uint32_t a3) {
  asm volatile("ds_read_b128 %0, %4\n\t"
               "ds_read_b128 %1, %5\n\t"
               "ds_read_b128 %2, %6\n\t"
               "ds_read_b128 %3, %7"
               : "=&v"(d0), "=&v"(d1), "=&v"(d2), "=&v"(d3)
               : "v"(a0), "v"(a1), "v"(a2), "v"(a3));
}
// Counted lgkm wait + scheduling fence. The sched_barrier is REQUIRED: hipcc
// hoists register-only MFMA past inline-asm waitcnt ("memory" doesn't order it).
template <int N>
__device__ __forceinline__ void lgkm_wait_sb() {
  asm volatile("s_waitcnt lgkmcnt(%0)" :: "n"(N) : "memory");
  __builtin_amdgcn_sched_barrier(0);
}
// v_cvt_pk_bf16_f32: two f32 -> packed 2xbf16 in one u32 (lo <- first arg).
__device__ __forceinline__ uint32_t cvtpk(float lo, float hi) {
  uint32_t r;
  asm("v_cvt_pk_bf16_f32 %0, %1, %2" : "=v"(r) : "v"(lo), "v"(hi));
  return r;
}
// P-redistribution on the VALU pipe (replaces 8 ds_bpermute + 4 cndmask).
// Semantics (documented): permlane32_swap: first.upper32 <-> second.lower32;
// permlane16_swap: first.odd-16rows <-> second.even-16rows. With per-16-lane-group
// values a={a0,a1,a2,a3}, b={b0,b1,b2,b3}:
//   after p32: a'={a0,a1,b0,b1} b'={a2,a3,b2,b3}
//   after p16: a''={a0,a2,b0,b2} b''={a1,a3,b1,b3}
// == exactly fragment words w0/w1 (a'') and w2/w3 (b'') of the PV A-operand.
// R2 LESSON: raw back-to-back asm permlanes read VGPRs written by the immediately
// preceding VALU/permlane op -> DPP read-after-VALU-write hazard (compiler inserts
// wait states only for INTRINSICS, not inside raw asm) -> stale lanes, absmax 1e-2.
// Use the builtins so the compiler handles hazards; s_nop-padded asm fallback.
__device__ __forceinline__ void plane_swap(uint32_t& a, uint32_t& b) {
#if __has_builtin(__builtin_amdgcn_permlane32_swap) && __has_builtin(__builtin_amdgcn_permlane16_swap)
  auto r1 = __builtin_amdgcn_permlane32_swap(a, b, false, false);
  auto r2 = __builtin_amdgcn_permlane16_swap(r1[0], r1[1], false, false);
  a = r2[0];
  b = r2[1];
#else
  asm("s_nop 1\n\t"
      "v_permlane32_swap_b32 %0, %1\n\t"
      "s_nop 1\n\t"
      "v_permlane16_swap_b32 %0, %1\n\t"
      "s_nop 1"
      : "+v"(a), "+v"(b));
#endif
}

// ---------------- fused prep: cvt inputs + transpose weights ----------------
__global__ __launch_bounds__(256) void prep_kernel(const float* __restrict__ qIn, const float* __restrict__ kvIn,
                                                   const float* __restrict__ w0, const float* __restrict__ w1,
                                                   const float* __restrict__ w2, const float* __restrict__ w3,
                                                   u16* __restrict__ oq, u16* __restrict__ okv,
                                                   u16* __restrict__ o0, u16* __restrict__ o1,
                                                   u16* __restrict__ o2, u16* __restrict__ o3) {
  __shared__ float tile[32][33];
  const int bid = blockIdx.x;
  const int t = threadIdx.x;
  if (bid < 16384) {
    const float* in = (bid >= 8192) ? kvIn : qIn;
    u16* out = (bid >= 8192) ? okv : oq;
    size_t i = (size_t)(bid & 8191) * 256 + t;
    float4 v = ((const float4*)in)[i];
    u16x4 o;
    o.x = f2bf(v.x); o.y = f2bf(v.y); o.z = f2bf(v.z); o.w = f2bf(v.w);
    ((u16x4*)out)[i] = o;
  } else {
    const int idx = bid - 16384;
    const int z = idx >> 10;
    const int rem = idx & 1023;
    const float* in; u16* out;
    switch (z) {
      case 0: in = w0; out = o0; break;
      case 1: in = w1; out = o1; break;
      case 2: in = w2; out = o2; break;
      default: in = w3; out = o3; break;
    }
    const int tx = t & 31, ty = t >> 5;
    const int x0 = (rem & 31) * 32;
    const int y0 = (rem >> 5) * 32;
#pragma unroll
    for (int j = 0; j < 32; j += 8)
      tile[ty + j][tx] = in[(size_t)(y0 + ty + j) * EDIM + x0 + tx];
    __syncthreads();
#pragma unroll
    for (int j = 0; j < 32; j += 8)
      out[(size_t)(x0 + ty + j) * EDIM + (y0 + tx)] = f2bf(tile[tx][ty + j]);
  }
}

// ---------------- BK=64 GEMM core (XOR-swizzled LDS, 128x128 tile) ----------------
struct GemmCore {
  template <typename EpiF>
  static __device__ __forceinline__ void run(const u16* __restrict__ A, const u16* __restrict__ Bt,
                                             int m0, int n0, u16* As, u16* Bs, EpiF epi) {
    const int tid = threadIdx.x;
    const int l = tid & 63;
    const int w = tid >> 6;
    const int wm = (w >> 1) * 64;
    const int wn = (w & 1) * 64;
    const int fm = l & 15;
    const int q4 = l >> 4;
    const int f7 = fm & 7;
    f32x4 acc[4][4] = {};
    for (int k0 = 0; k0 < EDIM; k0 += 64) {
      __syncthreads();
#pragma unroll
      for (int ii = 0; ii < 4; ++ii) {
        const int rloc = w * 32 + ii * 8 + (l >> 3);
        const int cs = (l & 7) ^ (rloc & 7);
        async16(A + (size_t)(m0 + rloc) * EDIM + k0 + cs * 8, &As[(w * 32 + ii * 8) * 64 + l * 8]);
        async16(Bt + (size_t)(n0 + rloc) * EDIM + k0 + cs * 8, &Bs[(w * 32 + ii * 8) * 64 + l * 8]);
      }
      __syncthreads();
#pragma unroll
      for (int ks = 0; ks < 2; ++ks) {
        const int coff = ((ks * 4 + q4) ^ f7) * 8;
        bf16x8 a[4], b[4];
#pragma unroll
        for (int i = 0; i < 4; ++i) a[i] = *(const bf16x8*)&As[(wm + i * 16 + fm) * 64 + coff];
#pragma unroll
        for (int j = 0; j < 4; ++j) b[j] = *(const bf16x8*)&Bs[(wn + j * 16 + fm) * 64 + coff];
#pragma unroll
        for (int i = 0; i < 4; ++i)
#pragma unroll
          for (int j = 0; j < 4; ++j)
            acc[i][j] = __builtin_amdgcn_mfma_f32_16x16x32_bf16(a[i], b[j], acc[i][j], 0, 0, 0);
      }
    }
    const int rr = q4 * 4;
#pragma unroll
    for (int i = 0; i < 4; ++i)
#pragma unroll
      for (int j = 0; j < 4; ++j)
#pragma unroll
        for (int r = 0; r < 4; ++r)
          epi(m0 + wm + i * 16 + rr + r, n0 + wn + j * 16 + fm, acc[i][j][r]);
  }
};

__global__ __launch_bounds__(256) void qkv_gemm(const u16* __restrict__ xq, const u16* __restrict__ xkv,
                                                const u16* __restrict__ WqT, const u16* __restrict__ WkT,
                                                const u16* __restrict__ WvT,
                                                u16* __restrict__ Qb, u16* __restrict__ Kb,
                                                u16* __restrict__ Vt,
                                                const unsigned char* __restrict__ mask,
                                                unsigned char* __restrict__ flags) {
  __shared__ __align__(16) u16 As[128 * 64];
  __shared__ __align__(16) u16 Bs[128 * 64];
  __shared__ int wany[4];
  const int z = blockIdx.z;
  if (z == 3) {
    // mask tile scan: 512 blocks x 16 tiles = 8192 (bh, 128x128-tile) units.
    const int t = threadIdx.x;
    const int unit0 = (blockIdx.x * 8 + blockIdx.y) * 16;
#pragma unroll 1
    for (int u = 0; u < 16; ++u) {
      const int idx = unit0 + u;
      const int bh = idx >> 8;
      const int tile16 = idx & 255;
      const int qt = tile16 >> 4, kt = tile16 & 15;
      const int r = t >> 1;
      const size_t base = ((size_t)bh * LQ + qt * 128 + r) * LQ + kt * 128 + (t & 1) * 64;
      const uint4* p = (const uint4*)(mask + base);
      uint4 a = p[0], c = p[1], d = p[2], e = p[3];
      uint32_t any = a.x | a.y | a.z | a.w | c.x | c.y | c.z | c.w |
                     d.x | d.y | d.z | d.w | e.x | e.y | e.z | e.w;
      int wa = __any(any != 0);
      if ((t & 63) == 0) wany[t >> 6] = wa;
      __syncthreads();
      if (t == 0)
        flags[(size_t)bh * 256 + tile16] = (unsigned char)(wany[0] | wany[1] | wany[2] | wany[3]);
      __syncthreads();  // wany reused next unit
    }
    return;
  }
  if (z == 0) {
    // scale*log2e folded into Q here: saves a v_mul per score in attn softmax
    GemmCore::run(xq, WqT, blockIdx.x * 128, blockIdx.y * 128, As, Bs,
                  [&](int gm, int gn, float v) { Qb[(size_t)gm * EDIM + gn] = f2bf(v * SCALE_LOG2E); });
  } else if (z == 1) {
    GemmCore::run(xkv, WkT, blockIdx.x * 128, blockIdx.y * 128, As, Bs,
                  [&](int gm, int gn, float v) { Kb[(size_t)gm * EDIM + gn] = f2bf(v); });
  } else {
    GemmCore::run(WvT, xkv, blockIdx.y * 128, blockIdx.x * 128, As, Bs,
                  [&](int gm, int gn, float v) {
                    Vt[((size_t)(gn >> 11) * 1024 + gm) * 2048 + (gn & 2047)] = f2bf(v);
                  });
  }
}

__global__ __launch_bounds__(256) void out_gemm(const u16* __restrict__ ctx, const u16* __restrict__ WfcT,
                                                float* __restrict__ out) {
  __shared__ __align__(16) u16 As[128 * 64];
  __shared__ __align__(16) u16 Bs[128 * 64];
  GemmCore::run(ctx, WfcT, blockIdx.x * 128, blockIdx.y * 128, As, Bs,
                [&](int gm, int gn, float v) { out[(size_t)gm * EDIM + gn] = v; });
}

// ---------------- flash attention v6b: P-exchange via permlane BUILTINS ----------------
// Same structure as v6 (R2): QK^T swapped operands, in-register P, all-16 V reads
// issued up front with two counted drains. Only change vs R2: plane_swap goes
// through __builtin_amdgcn_permlane{32,16}_swap so the compiler inserts the DPP
// hazard wait-states that raw asm omitted (R2's correctness failure).
__global__ __launch_bounds__(256, 2) void attn_kernel(const u16* __restrict__ Qb, const u16* __restrict__ Kb,
                                                      const u16* __restrict__ Vt,
                                                      const unsigned char* __restrict__ mask,
                                                      const unsigned char* __restrict__ flags,
                                                      u16* __restrict__ ctx) {
  __shared__ __align__(16) u16 Ktile[2][64 * 128];   // [key][d] rows 256B = 16 chunks, XOR-swizzled
  __shared__ __align__(16) u16 Vtile[2][128 * 64];   // [d][key] rows 128B = 8 chunks, XOR-swizzled
  const int tid = threadIdx.x;
  const int l = tid & 63;
  const int w = tid >> 6;
  const int qt = blockIdx.x;
  const int h = blockIdx.y;
  const int b = blockIdx.z;
  const int fm = l & 15;
  const int q4 = l >> 4;
  const int fk = q4 * 8;
  const int f7 = fm & 7;
  const int qbase = qt * 128 + w * 32;
  const int bh = b * HN + h;

  const u16* Kbh = Kb + (size_t)b * LQ * EDIM + h * DH;
  const u16* Vth = Vt + (size_t)bh * DH * LQ;
  const size_t mbase = (size_t)bh * (size_t)LQ * LQ;

  const unsigned char* tf = flags + (size_t)bh * 256 + qt * 16;
  uint32_t fmask = 0;
#pragma unroll
  for (int i = 0; i < 16; ++i) fmask |= (tf[i] ? 1u : 0u) << i;

  // Q fragments (issued before DMA so vmcnt ordering keeps them oldest)
  bf16x8 qf[2][4];
#pragma unroll
  for (int mt = 0; mt < 2; ++mt)
#pragma unroll
    for (int ks = 0; ks < 4; ++ks)
      qf[mt][ks] = *(const bf16x8*)(Qb + (size_t)(b * LQ + qbase + mt * 16 + fm) * EDIM + h * DH + ks * 32 + fk);

  auto stageK = [&](int kt_, int buf) {
#pragma unroll
    for (int ii = 0; ii < 4; ++ii) {
      const int i = w * 4 + ii;
      const int row = i * 4 + (l >> 4);          // key row 0..63
      const int g = (l & 15) ^ (row & 7);        // global chunk fetched into slot l&15
      async16(Kbh + (size_t)(kt_ * 64 + row) * EDIM + g * 8, &Ktile[buf][i * 512 + l * 8]);
    }
  };
  auto stageV = [&](int kt_, int buf) {
#pragma unroll
    for (int ii = 0; ii < 4; ++ii) {
      const int i = w * 4 + ii;
      const int row = i * 8 + (l >> 3);          // d row 0..127
      const int g = (l & 7) ^ (row & 7);
      async16(Vth + (size_t)row * LQ + kt_ * 64 + g * 8, &Vtile[buf][i * 512 + l * 8]);
    }
  };

  stageK(0, 0);
  stageV(0, 0);

  f32x4 o[2][8] = {};
  float lsumv[2] = {0.f, 0.f};

  for (int it = 0; it < 32; ++it) {
    const int cur = it & 1;
    // one barrier: (a) drains own K/V(it) DMA (issued a full iter ago -> ~free),
    // (b) all waves done reading buffers [1-cur] from iter it-1.
    __syncthreads();
    if (it + 1 < 32) { stageK(it + 1, 1 - cur); stageV(it + 1, 1 - cur); }

    const u16* KT = &Ktile[cur][0];
    const u16* VT = &Vtile[cur][0];

    // ---- St = K Q^T: 2-deep pipelined K-frag reads (issue ks+1 while mul ks)
    f32x4 st[4][2] = {};
    bf16x8 kf[2][4];
    {
      const int slot = q4 ^ f7;                  // ks=0 chunk
      ldsr4_issue(kf[0][0], kf[0][1], kf[0][2], kf[0][3],
                  lds_b(KT + (0 * 16 + fm) * 128 + slot * 8),
                  lds_b(KT + (1 * 16 + fm) * 128 + slot * 8),
                  lds_b(KT + (2 * 16 + fm) * 128 + slot * 8),
                  lds_b(KT + (3 * 16 + fm) * 128 + slot * 8));
    }
#pragma unroll
    for (int ks = 0; ks < 4; ++ks) {
      const int c = ks & 1;
      if (ks + 1 < 4) {
        const int slot = ((ks + 1) * 4 + q4) ^ f7;
        ldsr4_issue(kf[c ^ 1][0], kf[c ^ 1][1], kf[c ^ 1][2], kf[c ^ 1][3],
                    lds_b(KT + (0 * 16 + fm) * 128 + slot * 8),
                    lds_b(KT + (1 * 16 + fm) * 128 + slot * 8),
                    lds_b(KT + (2 * 16 + fm) * 128 + slot * 8),
                    lds_b(KT + (3 * 16 + fm) * 128 + slot * 8));
        lgkm_wait_sb<4>();                       // oldest 4 (slot ks) landed
      } else {
        lgkm_wait_sb<0>();
      }
      __builtin_amdgcn_s_setprio(1);
#pragma unroll
      for (int mt = 0; mt < 2; ++mt) {
        st[0][mt] = __builtin_amdgcn_mfma_f32_16x16x32_bf16(kf[c][0], qf[mt][ks], st[0][mt], 0, 0, 0);
        st[1][mt] = __builtin_amdgcn_mfma_f32_16x16x32_bf16(kf[c][1], qf[mt][ks], st[1][mt], 0, 0, 0);
        st[2][mt] = __builtin_amdgcn_mfma_f32_16x16x32_bf16(kf[c][2], qf[mt][ks], st[2][mt], 0, 0, 0);
        st[3][mt] = __builtin_amdgcn_mfma_f32_16x16x32_bf16(kf[c][3], qf[mt][ks], st[3][mt], 0, 0, 0);
      }
      __builtin_amdgcn_s_setprio(0);
    }

    // ---- softmax (no max-subtraction; masked -> 0; scale pre-folded into Q)
    const int hasMask = (fmask >> (it >> 1)) & 1;
    uint32_t pk[2][4][2];
#pragma unroll
    for (int mt = 0; mt < 2; ++mt) {
      float sum = 0.f;
      if (hasMask) {
        const unsigned char* mrow = mask + mbase + (size_t)(qbase + mt * 16 + fm) * LQ + it * 64 + q4 * 4;
#pragma unroll
        for (int kt = 0; kt < 4; ++kt) {
          const uint32_t mv = *(const uint32_t*)(mrow + kt * 16);
#pragma unroll
          for (int r = 0; r < 4; ++r) {
            float e = ((mv >> (8 * r)) & 0xffu) ? 0.f : exp2f(st[kt][mt][r]);
            st[kt][mt][r] = e;
            sum += e;
          }
        }
      } else {
#pragma unroll
        for (int kt = 0; kt < 4; ++kt)
#pragma unroll
          for (int r = 0; r < 4; ++r) {
            float e = exp2f(st[kt][mt][r]);
            st[kt][mt][r] = e;
            sum += e;
          }
      }
      sum += __shfl_xor(sum, 16);
      sum += __shfl_xor(sum, 32);
      lsumv[mt] += sum;
#pragma unroll
      for (int kt = 0; kt < 4; ++kt) {
        pk[mt][kt][0] = cvtpk(st[kt][mt][0], st[kt][mt][1]);
        pk[mt][kt][1] = cvtpk(st[kt][mt][2], st[kt][mt][3]);
      }
    }

    // ---- O += P V: V reads for both ns issued up front; P frags built on the
    //      VALU (permlane) while the reads are in flight; two counted drains.
    {
      bf16x8 v0, v1, v2, v3, v4, v5, v6, v7;
      const int vs0 = q4 ^ f7;
      ldsr4_issue(v0, v1, v2, v3,
                  lds_b(VT + (0 * 16 + fm) * 64 + vs0 * 8), lds_b(VT + (1 * 16 + fm) * 64 + vs0 * 8),
                  lds_b(VT + (2 * 16 + fm) * 64 + vs0 * 8), lds_b(VT + (3 * 16 + fm) * 64 + vs0 * 8));
      ldsr4_issue(v4, v5, v6, v7,
                  lds_b(VT + (4 * 16 + fm) * 64 + vs0 * 8), lds_b(VT + (5 * 16 + fm) * 64 + vs0 * 8),
                  lds_b(VT + (6 * 16 + fm) * 64 + vs0 * 8), lds_b(VT + (7 * 16 + fm) * 64 + vs0 * 8));
      bf16x8 x0, x1, x2, x3, x4, x5, x6, x7;
      const int vs1 = (4 + q4) ^ f7;
      ldsr4_issue(x0, x1, x2, x3,
                  lds_b(VT + (0 * 16 + fm) * 64 + vs1 * 8), lds_b(VT + (1 * 16 + fm) * 64 + vs1 * 8),
                  lds_b(VT + (2 * 16 + fm) * 64 + vs1 * 8), lds_b(VT + (3 * 16 + fm) * 64 + vs1 * 8));
      ldsr4_issue(x4, x5, x6, x7,
                  lds_b(VT + (4 * 16 + fm) * 64 + vs1 * 8), lds_b(VT + (5 * 16 + fm) * 64 + vs1 * 8),
                  lds_b(VT + (6 * 16 + fm) * 64 + vs1 * 8), lds_b(VT + (7 * 16 + fm) * 64 + vs1 * 8));

      bf16x8 paf0, paf1;
      // ns=0 P frags (VALU; overlaps the V-read latency)
      {
        union { uint32_t u[4]; bf16x8 v; } fb;
        uint32_t e0 = pk[0][0][0], f0 = pk[0][1][0];
        uint32_t e1 = pk[0][0][1], f1 = pk[0][1][1];
        plane_swap(e0, f0); plane_swap(e1, f1);
        fb.u[0] = e0; fb.u[1] = e1; fb.u[2] = f0; fb.u[3] = f1;
        paf0 = fb.v;
        uint32_t g0 = pk[1][0][0], h0 = pk[1][1][0];
        uint32_t g1 = pk[1][0][1], h1 = pk[1][1][1];
        plane_swap(g0, h0); plane_swap(g1, h1);
        fb.u[0] = g0; fb.u[1] = g1; fb.u[2] = h0; fb.u[3] = h1;
        paf1 = fb.v;
      }
      lgkm_wait_sb<8>();   // v0..v7 landed (x0..x7 = 8 newest still outstanding)
      __builtin_amdgcn_s_setprio(1);
      o[0][0] = __builtin_amdgcn_mfma_f32_16x16x32_bf16(paf0, v0, o[0][0], 0, 0, 0);
      o[1][0] = __builtin_amdgcn_mfma_f32_16x16x32_bf16(paf1, v0, o[1][0], 0, 0, 0);
      o[0][1] = __builtin_amdgcn_mfma_f32_16x16x32_bf16(paf0, v1, o[0][1], 0, 0, 0);
      o[1][1] = __builtin_amdgcn_mfma_f32_16x16x32_bf16(paf1, v1, o[1][1], 0, 0, 0);
      o[0][2] = __builtin_amdgcn_mfma_f32_16x16x32_bf16(paf0, v2, o[0][2], 0, 0, 0);
      o[1][2] = __builtin_amdgcn_mfma_f32_16x16x32_bf16(paf1, v2, o[1][2], 0, 0, 0);
      o[0][3] = __builtin_amdgcn_mfma_f32_16x16x32_bf16(paf0, v3, o[0][3], 0, 0, 0);
      o[1][3] = __builtin_amdgcn_mfma_f32_16x16x32_bf16(paf1, v3, o[1][3], 0, 0, 0);
      o[0][4] = __builtin_amdgcn_mfma_f32_16x16x32_bf16(paf0, v4, o[0][4], 0, 0, 0);
      o[1][4] = __builtin_amdgcn_mfma_f32_16x16x32_bf16(paf1, v4, o[1][4], 0, 0, 0);
      o[0][5] = __builtin_amdgcn_mfma_f32_16x16x32_bf16(paf0, v5, o[0][5], 0, 0, 0);
      o[1][5] = __builtin_amdgcn_mfma_f32_16x16x32_bf16(paf1, v5, o[1][5], 0, 0, 0);
      o[0][6] = __builtin_amdgcn_mfma_f32_16x16x32_bf16(paf0, v6, o[0][6], 0, 0, 0);
      o[1][6] = __builtin_amdgcn_mfma_f32_16x16x32_bf16(paf1, v6, o[1][6], 0, 0, 0);
      o[0][7] = __builtin_amdgcn_mfma_f32_16x16x32_bf16(paf0, v7, o[0][7], 0, 0, 0);
      o[1][7] = __builtin_amdgcn_mfma_f32_16x16x32_bf16(paf1, v7, o[1][7], 0, 0, 0);
      __builtin_amdgcn_s_setprio(0);
      // ns=1 P frags
      {
        union { uint32_t u[4]; bf16x8 v; } fb;
        uint32_t e0 = pk[0][2][0], f0 = pk[0][3][0];
        uint32_t e1 = pk[0][2][1], f1 = pk[0][3][1];
        plane_swap(e0, f0); plane_swap(e1, f1);
        fb.u[0] = e0; fb.u[1] = e1; fb.u[2] = f0; fb.u[3] = f1;
        paf0 = fb.v;
        uint32_t g0 = pk[1][2][0], h0 = pk[1][3][0];
        uint32_t g1 = pk[1][2][1], h1 = pk[1][3][1];
        plane_swap(g0, h0); plane_swap(g1, h1);
        fb.u[0] = g0; fb.u[1] = g1; fb.u[2] = h0; fb.u[3] = h1;
        paf1 = fb.v;
      }
      lgkm_wait_sb<0>();   // x0..x7 landed
      __builtin_amdgcn_s_setprio(1);
      o[0][0] = __builtin_amdgcn_mfma_f32_16x16x32_bf16(paf0, x0, o[0][0], 0, 0, 0);
      o[1][0] = __builtin_amdgcn_mfma_f32_16x16x32_bf16(paf1, x0, o[1][0], 0, 0, 0);
      o[0][1] = __builtin_amdgcn_mfma_f32_16x16x32_bf16(paf0, x1, o[0][1], 0, 0, 0);
      o[1][1] = __builtin_amdgcn_mfma_f32_16x16x32_bf16(paf1, x1, o[1][1], 0, 0, 0);
      o[0][2] = __builtin_amdgcn_mfma_f32_16x16x32_bf16(paf0, x2, o[0][2], 0, 0, 0);
      o[1][2] = __builtin_amdgcn_mfma_f32_16x16x32_bf16(paf1, x2, o[1][2], 0, 0, 0);
      o[0][3] = __builtin_amdgcn_mfma_f32_16x16x32_bf16(paf0, x3, o[0][3], 0, 0, 0);
      o[1][3] = __builtin_amdgcn_mfma_f32_16x16x32_bf16(paf1, x3, o[1][3], 0, 0, 0);
      o[0][4] = __builtin_amdgcn_mfma_f32_16x16x32_bf16(paf0, x4, o[0][4], 0, 0, 0);
      o[1][4] = __builtin_amdgcn_mfma_f32_16x16x32_bf16(paf1, x4, o[1][4], 0, 0, 0);
      o[0][5] = __builtin_amdgcn_mfma_f32_16x16x32_bf16(paf0, x5, o[0][5], 0, 0, 0);
      o[1][5] = __builtin_amdgcn_mfma_f32_16x16x32_bf16(paf1, x5, o[1][5], 0, 0, 0);
      o[0][6] = __builtin_amdgcn_mfma_f32_16x16x32_bf16(paf0, x6, o[0][6], 0, 0, 0);
      o[1][6] = __builtin_amdgcn_mfma_f32_16x16x32_bf16(paf1, x6, o[1][6], 0, 0, 0);
      o[0][7] = __builtin_amdgcn_mfma_f32_16x16x32_bf16(paf0, x7, o[0][7], 0, 0, 0);
      o[1][7] = __builtin_amdgcn_mfma_f32_16x16x32_bf16(paf1, x7, o[1][7], 0, 0, 0);
      __builtin_amdgcn_s_setprio(0);
    }
  }

  // ---- epilogue: ctx = O / lsum. lsum for q=16mt+(q4*4+r) lives on lane fm'=q4*4+r (q4'=0).
#pragma unroll
  for (int mt = 0; mt < 2; ++mt)
#pragma unroll
    for (int r = 0; r < 4; ++r) {
      float inv = 1.f / __shfl(lsumv[mt], q4 * 4 + r);
      int gq = b * LQ + qbase + mt * 16 + q4 * 4 + r;
#pragma unroll
      for (int dt = 0; dt < 8; ++dt)
        ctx[(size_t)gq * EDIM + h * DH + dt * 16 + fm] = f2bf(o[mt][dt][r] * inv);
    }
}

extern "C" void kernel_launch(void* const* d_in, const int* in_sizes, int n_in,
                              void* d_out, int out_size, void* d_ws, size_t ws_size,
                              hipStream_t stream) {
  const float* qIn = (const float*)d_in[0];
  const float* kvIn = (const float*)d_in[1];
  const unsigned char* mask = (const unsigned char*)d_in[2];
  const float* W_Q = (const float*)d_in[3];
  const float* W_K = (const float*)d_in[4];
  const float* W_V = (const float*)d_in[5];
  const float* W_fc = (const float*)d_in[6];
  float* out = (float*)d_out;

  uint8_t* ws = (uint8_t*)d_ws;
  const size_t MB = 1u << 20;
  u16* xq   = (u16*)(ws);
  u16* xkv  = (u16*)(ws + 16 * MB);
  u16* WqT  = (u16*)(ws + 32 * MB);
  u16* WkT  = (u16*)(ws + 34 * MB);
  u16* WvT  = (u16*)(ws + 36 * MB);
  u16* WfcT = (u16*)(ws + 38 * MB);
  u16* Qb   = (u16*)(ws + 40 * MB);
  u16* Kb   = (u16*)(ws + 56 * MB);
  u16* Vt   = (u16*)(ws + 72 * MB);
  u16* ctx  = (u16*)(ws + 88 * MB);
  unsigned char* flags = (unsigned char*)(ws + 104 * MB);

  prep_kernel<<<20480, 256, 0, stream>>>(qIn, kvIn, W_Q, W_K, W_V, W_fc,
                                         xq, xkv, WqT, WkT, WvT, WfcT);
  qkv_gemm<<<dim3(64, 8, 4), 256, 0, stream>>>(xq, xkv, WqT, WkT, WvT, Qb, Kb, Vt, mask, flags);
  attn_kernel<<<dim3(16, 8, 4), 256, 0, stream>>>(Qb, Kb, Vt, mask, flags, ctx);
  out_gemm<<<dim3(64, 8), 256, 0, stream>>>(ctx, WfcT, out);
}

// Round 5
// 826.550 us; speedup vs baseline: 1.0264x; 1.0033x over previous
//
#include <hip/hip_runtime.h>
#include <stdint.h>

#define LQ 2048
#define EDIM 1024
#define HN 8
#define DH 128
#define BATCH 4
#define SCALE_LOG2E 0.12753785051263942f  // (1/sqrt(128)) * log2(e) -- folded into Qb

typedef short bf16x8 __attribute__((ext_vector_type(8)));
typedef float f32x4 __attribute__((ext_vector_type(4)));
typedef unsigned short u16;
typedef unsigned short u16x4 __attribute__((ext_vector_type(4)));

__device__ __forceinline__ u16 f2bf(float f) {
  union { float f; uint32_t u; } c; c.f = f;
  uint32_t u = c.u;
  return (u16)((u + 0x7fffu + ((u >> 16) & 1u)) >> 16);
}

__device__ __forceinline__ void async16(const void* g, void* l) {
  __builtin_amdgcn_global_load_lds((const __attribute__((address_space(1))) void*)g,
                                   (__attribute__((address_space(3))) void*)l, 16, 0, 0);
}

// LDS byte address for inline-asm DS ops
__device__ __forceinline__ uint32_t lds_b(const u16* p) {
  return (uint32_t)(uintptr_t)(__attribute__((address_space(3))) const u16*)p;
}
// Issue-only 4x ds_read_b128 (NO drain). Outputs early-clobber; values valid only
// after a following counted lgkm wait. DS ops complete in order.
__device__ __forceinline__ void ldsr4_issue(bf16x8& d0, bf16x8& d1, bf16x8& d2, bf16x8& d3,
                                            uint32_t a0, uint32_t a1, uint32_t a2, uint32_t a3) {
  asm volatile("ds_read_b128 %0, %4\n\t"
               "ds_read_b128 %1, %5\n\t"
               "ds_read_b128 %2, %6\n\t"
               "ds_read_b128 %3, %7"
               : "=&v"(d0), "=&v"(d1), "=&v"(d2), "=&v"(d3)
               : "v"(a0), "v"(a1), "v"(a2), "v"(a3));
}
// Counted lgkm wait + scheduling fence. The sched_barrier is REQUIRED: hipcc
// hoists register-only MFMA past inline-asm waitcnt ("memory" doesn't order it).
template <int N>
__device__ __forceinline__ void lgkm_wait_sb() {
  asm volatile("s_waitcnt lgkmcnt(%0)" :: "n"(N) : "memory");
  __builtin_amdgcn_sched_barrier(0);
}
// v_cvt_pk_bf16_f32: two f32 -> packed 2xbf16 in one u32 (lo <- first arg).
__device__ __forceinline__ uint32_t cvtpk(float lo, float hi) {
  uint32_t r;
  asm("v_cvt_pk_bf16_f32 %0, %1, %2" : "=v"(r) : "v"(lo), "v"(hi));
  return r;
}
// P-redistribution on the VALU pipe. R3-validated builtin path (compiler inserts
// the DPP hazard wait-states raw asm omitted -- R2's correctness failure).
__device__ __forceinline__ void plane_swap(uint32_t& a, uint32_t& b) {
#if __has_builtin(__builtin_amdgcn_permlane32_swap) && __has_builtin(__builtin_amdgcn_permlane16_swap)
  auto r1 = __builtin_amdgcn_permlane32_swap(a, b, false, false);
  auto r2 = __builtin_amdgcn_permlane16_swap(r1[0], r1[1], false, false);
  a = r2[0];
  b = r2[1];
#else
  asm("s_nop 1\n\t"
      "v_permlane32_swap_b32 %0, %1\n\t"
      "s_nop 1\n\t"
      "v_permlane16_swap_b32 %0, %1\n\t"
      "s_nop 1"
      : "+v"(a), "+v"(b));
#endif
}
// DS-free butterfly sums (keep counted lgkm waits valid across softmax):
// permlaneN_swap(x,x) returns {out0,out1} with out0+out1 == x + x^N per lane
// (value-identical to the shfl_xor version -> bitwise-same lsum).
__device__ __forceinline__ float xorsum16(float x) {
#if __has_builtin(__builtin_amdgcn_permlane16_swap)
  union { float f; uint32_t u; } c; c.f = x;
  auto r = __builtin_amdgcn_permlane16_swap(c.u, c.u, false, false);
  union { uint32_t u; float f; } a, b; a.u = r[0]; b.u = r[1];
  return a.f + b.f;
#else
  return x + __shfl_xor(x, 16);   // correct fallback (slower: DS op)
#endif
}
__device__ __forceinline__ float xorsum32(float x) {
#if __has_builtin(__builtin_amdgcn_permlane32_swap)
  union { float f; uint32_t u; } c; c.f = x;
  auto r = __builtin_amdgcn_permlane32_swap(c.u, c.u, false, false);
  union { uint32_t u; float f; } a, b; a.u = r[0]; b.u = r[1];
  return a.f + b.f;
#else
  return x + __shfl_xor(x, 32);
#endif
}

// ---------------- fused prep: cvt inputs + transpose weights ----------------
__global__ __launch_bounds__(256) void prep_kernel(const float* __restrict__ qIn, const float* __restrict__ kvIn,
                                                   const float* __restrict__ w0, const float* __restrict__ w1,
                                                   const float* __restrict__ w2, const float* __restrict__ w3,
                                                   u16* __restrict__ oq, u16* __restrict__ okv,
                                                   u16* __restrict__ o0, u16* __restrict__ o1,
                                                   u16* __restrict__ o2, u16* __restrict__ o3) {
  __shared__ float tile[32][33];
  const int bid = blockIdx.x;
  const int t = threadIdx.x;
  if (bid < 16384) {
    const float* in = (bid >= 8192) ? kvIn : qIn;
    u16* out = (bid >= 8192) ? okv : oq;
    size_t i = (size_t)(bid & 8191) * 256 + t;
    float4 v = ((const float4*)in)[i];
    u16x4 o;
    o.x = f2bf(v.x); o.y = f2bf(v.y); o.z = f2bf(v.z); o.w = f2bf(v.w);
    ((u16x4*)out)[i] = o;
  } else {
    const int idx = bid - 16384;
    const int z = idx >> 10;
    const int rem = idx & 1023;
    const float* in; u16* out;
    switch (z) {
      case 0: in = w0; out = o0; break;
      case 1: in = w1; out = o1; break;
      case 2: in = w2; out = o2; break;
      default: in = w3; out = o3; break;
    }
    const int tx = t & 31, ty = t >> 5;
    const int x0 = (rem & 31) * 32;
    const int y0 = (rem >> 5) * 32;
#pragma unroll
    for (int j = 0; j < 32; j += 8)
      tile[ty + j][tx] = in[(size_t)(y0 + ty + j) * EDIM + x0 + tx];
    __syncthreads();
#pragma unroll
    for (int j = 0; j < 32; j += 8)
      out[(size_t)(x0 + ty + j) * EDIM + (y0 + tx)] = f2bf(tile[tx][ty + j]);
  }
}

// ---------------- BK=64 GEMM core (XOR-swizzled LDS, 128x128 tile) ----------------
struct GemmCore {
  template <typename EpiF>
  static __device__ __forceinline__ void run(const u16* __restrict__ A, const u16* __restrict__ Bt,
                                             int m0, int n0, u16* As, u16* Bs, EpiF epi) {
    const int tid = threadIdx.x;
    const int l = tid & 63;
    const int w = tid >> 6;
    const int wm = (w >> 1) * 64;
    const int wn = (w & 1) * 64;
    const int fm = l & 15;
    const int q4 = l >> 4;
    const int f7 = fm & 7;
    f32x4 acc[4][4] = {};
    for (int k0 = 0; k0 < EDIM; k0 += 64) {
      __syncthreads();
#pragma unroll
      for (int ii = 0; ii < 4; ++ii) {
        const int rloc = w * 32 + ii * 8 + (l >> 3);
        const int cs = (l & 7) ^ (rloc & 7);
        async16(A + (size_t)(m0 + rloc) * EDIM + k0 + cs * 8, &As[(w * 32 + ii * 8) * 64 + l * 8]);
        async16(Bt + (size_t)(n0 + rloc) * EDIM + k0 + cs * 8, &Bs[(w * 32 + ii * 8) * 64 + l * 8]);
      }
      __syncthreads();
#pragma unroll
      for (int ks = 0; ks < 2; ++ks) {
        const int coff = ((ks * 4 + q4) ^ f7) * 8;
        bf16x8 a[4], b[4];
#pragma unroll
        for (int i = 0; i < 4; ++i) a[i] = *(const bf16x8*)&As[(wm + i * 16 + fm) * 64 + coff];
#pragma unroll
        for (int j = 0; j < 4; ++j) b[j] = *(const bf16x8*)&Bs[(wn + j * 16 + fm) * 64 + coff];
#pragma unroll
        for (int i = 0; i < 4; ++i)
#pragma unroll
          for (int j = 0; j < 4; ++j)
            acc[i][j] = __builtin_amdgcn_mfma_f32_16x16x32_bf16(a[i], b[j], acc[i][j], 0, 0, 0);
      }
    }
    const int rr = q4 * 4;
#pragma unroll
    for (int i = 0; i < 4; ++i)
#pragma unroll
      for (int j = 0; j < 4; ++j)
#pragma unroll
        for (int r = 0; r < 4; ++r)
          epi(m0 + wm + i * 16 + rr + r, n0 + wn + j * 16 + fm, acc[i][j][r]);
  }
};

__global__ __launch_bounds__(256) void qkv_gemm(const u16* __restrict__ xq, const u16* __restrict__ xkv,
                                                const u16* __restrict__ WqT, const u16* __restrict__ WkT,
                                                const u16* __restrict__ WvT,
                                                u16* __restrict__ Qb, u16* __restrict__ Kb,
                                                u16* __restrict__ Vt,
                                                const unsigned char* __restrict__ mask,
                                                unsigned char* __restrict__ flags) {
  __shared__ __align__(16) u16 As[128 * 64];
  __shared__ __align__(16) u16 Bs[128 * 64];
  __shared__ int wany[4];
  const int z = blockIdx.z;
  if (z == 3) {
    // mask tile scan: 512 blocks x 16 tiles = 8192 (bh, 128x128-tile) units.
    const int t = threadIdx.x;
    const int unit0 = (blockIdx.x * 8 + blockIdx.y) * 16;
#pragma unroll 1
    for (int u = 0; u < 16; ++u) {
      const int idx = unit0 + u;
      const int bh = idx >> 8;
      const int tile16 = idx & 255;
      const int qt = tile16 >> 4, kt = tile16 & 15;
      const int r = t >> 1;
      const size_t base = ((size_t)bh * LQ + qt * 128 + r) * LQ + kt * 128 + (t & 1) * 64;
      const uint4* p = (const uint4*)(mask + base);
      uint4 a = p[0], c = p[1], d = p[2], e = p[3];
      uint32_t any = a.x | a.y | a.z | a.w | c.x | c.y | c.z | c.w |
                     d.x | d.y | d.z | d.w | e.x | e.y | e.z | e.w;
      int wa = __any(any != 0);
      if ((t & 63) == 0) wany[t >> 6] = wa;
      __syncthreads();
      if (t == 0)
        flags[(size_t)bh * 256 + tile16] = (unsigned char)(wany[0] | wany[1] | wany[2] | wany[3]);
      __syncthreads();  // wany reused next unit
    }
    return;
  }
  if (z == 0) {
    // scale*log2e folded into Q here: saves a v_mul per score in attn softmax
    GemmCore::run(xq, WqT, blockIdx.x * 128, blockIdx.y * 128, As, Bs,
                  [&](int gm, int gn, float v) { Qb[(size_t)gm * EDIM + gn] = f2bf(v * SCALE_LOG2E); });
  } else if (z == 1) {
    GemmCore::run(xkv, WkT, blockIdx.x * 128, blockIdx.y * 128, As, Bs,
                  [&](int gm, int gn, float v) { Kb[(size_t)gm * EDIM + gn] = f2bf(v); });
  } else {
    GemmCore::run(WvT, xkv, blockIdx.y * 128, blockIdx.x * 128, As, Bs,
                  [&](int gm, int gn, float v) {
                    Vt[((size_t)(gn >> 11) * 1024 + gm) * 2048 + (gn & 2047)] = f2bf(v);
                  });
  }
}

__global__ __launch_bounds__(256) void out_gemm(const u16* __restrict__ ctx, const u16* __restrict__ WfcT,
                                                float* __restrict__ out) {
  __shared__ __align__(16) u16 As[128 * 64];
  __shared__ __align__(16) u16 Bs[128 * 64];
  GemmCore::run(ctx, WfcT, blockIdx.x * 128, blockIdx.y * 128, As, Bs,
                [&](int gm, int gn, float v) { out[(size_t)gm * EDIM + gn] = v; });
}

// ---------------- flash attention v7: softmax/PV overlap, DS-free softmax ----------------
// v6b -> v7: (1) ns=0 V reads issued in the QK tail (lgkmcnt(8) proves K landed;
// V flies under ks=3 MFMAs + softmax-A); (2) softmax split: kt0/1 before PV ns=0,
// kt2/3 + lsum reduction BETWEEN the PV clusters (VALU hides under MFMA);
// (3) lsum reduction via self-permlane (DS-free -> counted lgkm waits stay valid);
// (4) bijective panel-grouping swizzle: all 16 q-tiles of a (b,h) KV panel on one
// XCD (4 panels/XCD = 4MB = L2 size).
__global__ __launch_bounds__(256, 2) void attn_kernel(const u16* __restrict__ Qb, const u16* __restrict__ Kb,
                                                      const u16* __restrict__ Vt,
                                                      const unsigned char* __restrict__ mask,
                                                      const unsigned char* __restrict__ flags,
                                                      u16* __restrict__ ctx) {
  __shared__ __align__(16) u16 Ktile[2][64 * 128];   // [key][d] rows 256B = 16 chunks, XOR-swizzled
  __shared__ __align__(16) u16 Vtile[2][128 * 64];   // [d][key] rows 128B = 8 chunks, XOR-swizzled
  const int tid = threadIdx.x;
  const int l = tid & 63;
  const int w = tid >> 6;
  // panel-grouping swizzle: flat -> (qt, h, b) with each (b,h) panel's 16 q-tiles
  // on one XCD (assumes round-robin dispatch, id%8 = XCD; bijective either way).
  const int flat = blockIdx.x;          // 0..511
  const int xcd = flat & 7;
  const int idx = flat >> 3;            // 0..63
  const int panel = xcd * 4 + (idx >> 4);  // 0..31
  const int qt = idx & 15;
  const int h = panel & 7;
  const int b = panel >> 3;
  const int fm = l & 15;
  const int q4 = l >> 4;
  const int fk = q4 * 8;
  const int f7 = fm & 7;
  const int qbase = qt * 128 + w * 32;
  const int bh = b * HN + h;

  const u16* Kbh = Kb + (size_t)b * LQ * EDIM + h * DH;
  const u16* Vth = Vt + (size_t)bh * DH * LQ;
  const size_t mbase = (size_t)bh * (size_t)LQ * LQ;

  const unsigned char* tf = flags + (size_t)bh * 256 + qt * 16;
  uint32_t fmask = 0;
#pragma unroll
  for (int i = 0; i < 16; ++i) fmask |= (tf[i] ? 1u : 0u) << i;

  // Q fragments (issued before DMA so vmcnt ordering keeps them oldest)
  bf16x8 qf[2][4];
#pragma unroll
  for (int mt = 0; mt < 2; ++mt)
#pragma unroll
    for (int ks = 0; ks < 4; ++ks)
      qf[mt][ks] = *(const bf16x8*)(Qb + (size_t)(b * LQ + qbase + mt * 16 + fm) * EDIM + h * DH + ks * 32 + fk);

  auto stageK = [&](int kt_, int buf) {
#pragma unroll
    for (int ii = 0; ii < 4; ++ii) {
      const int i = w * 4 + ii;
      const int row = i * 4 + (l >> 4);          // key row 0..63
      const int g = (l & 15) ^ (row & 7);        // global chunk fetched into slot l&15
      async16(Kbh + (size_t)(kt_ * 64 + row) * EDIM + g * 8, &Ktile[buf][i * 512 + l * 8]);
    }
  };
  auto stageV = [&](int kt_, int buf) {
#pragma unroll
    for (int ii = 0; ii < 4; ++ii) {
      const int i = w * 4 + ii;
      const int row = i * 8 + (l >> 3);          // d row 0..127
      const int g = (l & 7) ^ (row & 7);
      async16(Vth + (size_t)row * LQ + kt_ * 64 + g * 8, &Vtile[buf][i * 512 + l * 8]);
    }
  };

  stageK(0, 0);
  stageV(0, 0);

  f32x4 o[2][8] = {};
  float lsumv[2] = {0.f, 0.f};

  for (int it = 0; it < 32; ++it) {
    const int cur = it & 1;
    // one barrier: (a) drains own K/V(it) DMA (issued a full iter ago -> ~free),
    // (b) all waves done reading buffers [1-cur] from iter it-1.
    __syncthreads();
    if (it + 1 < 32) { stageK(it + 1, 1 - cur); stageV(it + 1, 1 - cur); }

    const u16* KT = &Ktile[cur][0];
    const u16* VT = &Vtile[cur][0];

    // ---- St = K Q^T: 2-deep pipelined K-frag reads; ns=0 V reads issued in tail
    f32x4 st[4][2] = {};
    bf16x8 kf[2][4];
    bf16x8 v0, v1, v2, v3, v4, v5, v6, v7;   // ns=0 V frags (issued at ks=3)
    bf16x8 x0, x1, x2, x3, x4, x5, x6, x7;   // ns=1 V frags (issued after softmax-A)
    {
      const int slot = q4 ^ f7;                  // ks=0 chunk
      ldsr4_issue(kf[0][0], kf[0][1], kf[0][2], kf[0][3],
                  lds_b(KT + (0 * 16 + fm) * 128 + slot * 8),
                  lds_b(KT + (1 * 16 + fm) * 128 + slot * 8),
                  lds_b(KT + (2 * 16 + fm) * 128 + slot * 8),
                  lds_b(KT + (3 * 16 + fm) * 128 + slot * 8));
    }
#pragma unroll
    for (int ks = 0; ks < 3; ++ks) {
      const int c = ks & 1;
      const int slot = ((ks + 1) * 4 + q4) ^ f7;
      ldsr4_issue(kf[c ^ 1][0], kf[c ^ 1][1], kf[c ^ 1][2], kf[c ^ 1][3],
                  lds_b(KT + (0 * 16 + fm) * 128 + slot * 8),
                  lds_b(KT + (1 * 16 + fm) * 128 + slot * 8),
                  lds_b(KT + (2 * 16 + fm) * 128 + slot * 8),
                  lds_b(KT + (3 * 16 + fm) * 128 + slot * 8));
      lgkm_wait_sb<4>();                       // oldest 4 (slot ks) landed
      __builtin_amdgcn_s_setprio(1);
#pragma unroll
      for (int mt = 0; mt < 2; ++mt) {
        st[0][mt] = __builtin_amdgcn_mfma_f32_16x16x32_bf16(kf[c][0], qf[mt][ks], st[0][mt], 0, 0, 0);
        st[1][mt] = __builtin_amdgcn_mfma_f32_16x16x32_bf16(kf[c][1], qf[mt][ks], st[1][mt], 0, 0, 0);
        st[2][mt] = __builtin_amdgcn_mfma_f32_16x16x32_bf16(kf[c][2], qf[mt][ks], st[2][mt], 0, 0, 0);
        st[3][mt] = __builtin_amdgcn_mfma_f32_16x16x32_bf16(kf[c][3], qf[mt][ks], st[3][mt], 0, 0, 0);
      }
      __builtin_amdgcn_s_setprio(0);
    }
    {
      // ks = 3 tail: issue ns=0 V reads (8); lgkmcnt(8) proves the 4 K reads landed
      // while the V reads fly under the ks=3 MFMAs and softmax-A.
      const int vs0 = q4 ^ f7;
      ldsr4_issue(v0, v1, v2, v3,
                  lds_b(VT + (0 * 16 + fm) * 64 + vs0 * 8), lds_b(VT + (1 * 16 + fm) * 64 + vs0 * 8),
                  lds_b(VT + (2 * 16 + fm) * 64 + vs0 * 8), lds_b(VT + (3 * 16 + fm) * 64 + vs0 * 8));
      ldsr4_issue(v4, v5, v6, v7,
                  lds_b(VT + (4 * 16 + fm) * 64 + vs0 * 8), lds_b(VT + (5 * 16 + fm) * 64 + vs0 * 8),
                  lds_b(VT + (6 * 16 + fm) * 64 + vs0 * 8), lds_b(VT + (7 * 16 + fm) * 64 + vs0 * 8));
      lgkm_wait_sb<8>();
      __builtin_amdgcn_s_setprio(1);
#pragma unroll
      for (int mt = 0; mt < 2; ++mt) {
        st[0][mt] = __builtin_amdgcn_mfma_f32_16x16x32_bf16(kf[1][0], qf[mt][3], st[0][mt], 0, 0, 0);
        st[1][mt] = __builtin_amdgcn_mfma_f32_16x16x32_bf16(kf[1][1], qf[mt][3], st[1][mt], 0, 0, 0);
        st[2][mt] = __builtin_amdgcn_mfma_f32_16x16x32_bf16(kf[1][2], qf[mt][3], st[2][mt], 0, 0, 0);
        st[3][mt] = __builtin_amdgcn_mfma_f32_16x16x32_bf16(kf[1][3], qf[mt][3], st[3][mt], 0, 0, 0);
      }
      __builtin_amdgcn_s_setprio(0);
    }

    // ---- softmax phase A: kt 0,1 (scale pre-folded into Q; masked -> 0)
    const int hasMask = (fmask >> (it >> 1)) & 1;
    uint32_t pk[2][4][2];
    float sA[2], sB[2];
    bf16x8 paf0, paf1;
#pragma unroll
    for (int mt = 0; mt < 2; ++mt) {
      float sum = 0.f;
      if (hasMask) {
        const unsigned char* mrow = mask + mbase + (size_t)(qbase + mt * 16 + fm) * LQ + it * 64 + q4 * 4;
#pragma unroll
        for (int kt = 0; kt < 2; ++kt) {
          const uint32_t mv = *(const uint32_t*)(mrow + kt * 16);
#pragma unroll
          for (int r = 0; r < 4; ++r) {
            float e = ((mv >> (8 * r)) & 0xffu) ? 0.f : exp2f(st[kt][mt][r]);
            st[kt][mt][r] = e;
            sum += e;
          }
        }
      } else {
#pragma unroll
        for (int kt = 0; kt < 2; ++kt)
#pragma unroll
          for (int r = 0; r < 4; ++r) {
            float e = exp2f(st[kt][mt][r]);
            st[kt][mt][r] = e;
            sum += e;
          }
      }
      sA[mt] = sum;
      pk[mt][0][0] = cvtpk(st[0][mt][0], st[0][mt][1]);
      pk[mt][0][1] = cvtpk(st[0][mt][2], st[0][mt][3]);
      pk[mt][1][0] = cvtpk(st[1][mt][0], st[1][mt][1]);
      pk[mt][1][1] = cvtpk(st[1][mt][2], st[1][mt][3]);
    }
    {
      union { uint32_t u[4]; bf16x8 v; } fb;
      uint32_t e0 = pk[0][0][0], f0 = pk[0][1][0];
      uint32_t e1 = pk[0][0][1], f1 = pk[0][1][1];
      plane_swap(e0, f0); plane_swap(e1, f1);
      fb.u[0] = e0; fb.u[1] = e1; fb.u[2] = f0; fb.u[3] = f1;
      paf0 = fb.v;
      uint32_t g0 = pk[1][0][0], h0 = pk[1][1][0];
      uint32_t g1 = pk[1][0][1], h1 = pk[1][1][1];
      plane_swap(g0, h0); plane_swap(g1, h1);
      fb.u[0] = g0; fb.u[1] = g1; fb.u[2] = h0; fb.u[3] = h1;
      paf1 = fb.v;
    }
    // issue ns=1 V reads now: land under PV ns=0's MFMAs
    {
      const int vs1 = (4 + q4) ^ f7;
      ldsr4_issue(x0, x1, x2, x3,
                  lds_b(VT + (0 * 16 + fm) * 64 + vs1 * 8), lds_b(VT + (1 * 16 + fm) * 64 + vs1 * 8),
                  lds_b(VT + (2 * 16 + fm) * 64 + vs1 * 8), lds_b(VT + (3 * 16 + fm) * 64 + vs1 * 8));
      ldsr4_issue(x4, x5, x6, x7,
                  lds_b(VT + (4 * 16 + fm) * 64 + vs1 * 8), lds_b(VT + (5 * 16 + fm) * 64 + vs1 * 8),
                  lds_b(VT + (6 * 16 + fm) * 64 + vs1 * 8), lds_b(VT + (7 * 16 + fm) * 64 + vs1 * 8));
    }
    lgkm_wait_sb<8>();   // v0..v7 (oldest 8) landed; x0..x7 still in flight
    __builtin_amdgcn_s_setprio(1);
    o[0][0] = __builtin_amdgcn_mfma_f32_16x16x32_bf16(paf0, v0, o[0][0], 0, 0, 0);
    o[1][0] = __builtin_amdgcn_mfma_f32_16x16x32_bf16(paf1, v0, o[1][0], 0, 0, 0);
    o[0][1] = __builtin_amdgcn_mfma_f32_16x16x32_bf16(paf0, v1, o[0][1], 0, 0, 0);
    o[1][1] = __builtin_amdgcn_mfma_f32_16x16x32_bf16(paf1, v1, o[1][1], 0, 0, 0);
    o[0][2] = __builtin_amdgcn_mfma_f32_16x16x32_bf16(paf0, v2, o[0][2], 0, 0, 0);
    o[1][2] = __builtin_amdgcn_mfma_f32_16x16x32_bf16(paf1, v2, o[1][2], 0, 0, 0);
    o[0][3] = __builtin_amdgcn_mfma_f32_16x16x32_bf16(paf0, v3, o[0][3], 0, 0, 0);
    o[1][3] = __builtin_amdgcn_mfma_f32_16x16x32_bf16(paf1, v3, o[1][3], 0, 0, 0);
    o[0][4] = __builtin_amdgcn_mfma_f32_16x16x32_bf16(paf0, v4, o[0][4], 0, 0, 0);
    o[1][4] = __builtin_amdgcn_mfma_f32_16x16x32_bf16(paf1, v4, o[1][4], 0, 0, 0);
    o[0][5] = __builtin_amdgcn_mfma_f32_16x16x32_bf16(paf0, v5, o[0][5], 0, 0, 0);
    o[1][5] = __builtin_amdgcn_mfma_f32_16x16x32_bf16(paf1, v5, o[1][5], 0, 0, 0);
    o[0][6] = __builtin_amdgcn_mfma_f32_16x16x32_bf16(paf0, v6, o[0][6], 0, 0, 0);
    o[1][6] = __builtin_amdgcn_mfma_f32_16x16x32_bf16(paf1, v6, o[1][6], 0, 0, 0);
    o[0][7] = __builtin_amdgcn_mfma_f32_16x16x32_bf16(paf0, v7, o[0][7], 0, 0, 0);
    o[1][7] = __builtin_amdgcn_mfma_f32_16x16x32_bf16(paf1, v7, o[1][7], 0, 0, 0);
    __builtin_amdgcn_s_setprio(0);

    // ---- softmax phase B: kt 2,3 + lsum reduction (VALU; interleaves with ns=0 MFMAs)
#pragma unroll
    for (int mt = 0; mt < 2; ++mt) {
      float sum = 0.f;
      if (hasMask) {
        const unsigned char* mrow = mask + mbase + (size_t)(qbase + mt * 16 + fm) * LQ + it * 64 + q4 * 4;
#pragma unroll
        for (int kt = 2; kt < 4; ++kt) {
          const uint32_t mv = *(const uint32_t*)(mrow + kt * 16);
#pragma unroll
          for (int r = 0; r < 4; ++r) {
            float e = ((mv >> (8 * r)) & 0xffu) ? 0.f : exp2f(st[kt][mt][r]);
            st[kt][mt][r] = e;
            sum += e;
          }
        }
      } else {
#pragma unroll
        for (int kt = 2; kt < 4; ++kt)
#pragma unroll
          for (int r = 0; r < 4; ++r) {
            float e = exp2f(st[kt][mt][r]);
            st[kt][mt][r] = e;
            sum += e;
          }
      }
      sB[mt] = sum;
      pk[mt][2][0] = cvtpk(st[2][mt][0], st[2][mt][1]);
      pk[mt][2][1] = cvtpk(st[2][mt][2], st[2][mt][3]);
      pk[mt][3][0] = cvtpk(st[3][mt][0], st[3][mt][1]);
      pk[mt][3][1] = cvtpk(st[3][mt][2], st[3][mt][3]);
    }
    {
      union { uint32_t u[4]; bf16x8 v; } fb;
      uint32_t e0 = pk[0][2][0], f0 = pk[0][3][0];
      uint32_t e1 = pk[0][2][1], f1 = pk[0][3][1];
      plane_swap(e0, f0); plane_swap(e1, f1);
      fb.u[0] = e0; fb.u[1] = e1; fb.u[2] = f0; fb.u[3] = f1;
      paf0 = fb.v;
      uint32_t g0 = pk[1][2][0], h0 = pk[1][3][0];
      uint32_t g1 = pk[1][2][1], h1 = pk[1][3][1];
      plane_swap(g0, h0); plane_swap(g1, h1);
      fb.u[0] = g0; fb.u[1] = g1; fb.u[2] = h0; fb.u[3] = h1;
      paf1 = fb.v;
    }
#pragma unroll
    for (int mt = 0; mt < 2; ++mt) {
      float t = sA[mt] + sB[mt];
      lsumv[mt] += xorsum32(xorsum16(t));   // value-identical to shfl_xor chain
    }

    lgkm_wait_sb<0>();   // x0..x7 landed
    __builtin_amdgcn_s_setprio(1);
    o[0][0] = __builtin_amdgcn_mfma_f32_16x16x32_bf16(paf0, x0, o[0][0], 0, 0, 0);
    o[1][0] = __builtin_amdgcn_mfma_f32_16x16x32_bf16(paf1, x0, o[1][0], 0, 0, 0);
    o[0][1] = __builtin_amdgcn_mfma_f32_16x16x32_bf16(paf0, x1, o[0][1], 0, 0, 0);
    o[1][1] = __builtin_amdgcn_mfma_f32_16x16x32_bf16(paf1, x1, o[1][1], 0, 0, 0);
    o[0][2] = __builtin_amdgcn_mfma_f32_16x16x32_bf16(paf0, x2, o[0][2], 0, 0, 0);
    o[1][2] = __builtin_amdgcn_mfma_f32_16x16x32_bf16(paf1, x2, o[1][2], 0, 0, 0);
    o[0][3] = __builtin_amdgcn_mfma_f32_16x16x32_bf16(paf0, x3, o[0][3], 0, 0, 0);
    o[1][3] = __builtin_amdgcn_mfma_f32_16x16x32_bf16(paf1, x3, o[1][3], 0, 0, 0);
    o[0][4] = __builtin_amdgcn_mfma_f32_16x16x32_bf16(paf0, x4, o[0][4], 0, 0, 0);
    o[1][4] = __builtin_amdgcn_mfma_f32_16x16x32_bf16(paf1, x4, o[1][4], 0, 0, 0);
    o[0][5] = __builtin_amdgcn_mfma_f32_16x16x32_bf16(paf0, x5, o[0][5], 0, 0, 0);
    o[1][5] = __builtin_amdgcn_mfma_f32_16x16x32_bf16(paf1, x5, o[1][5], 0, 0, 0);
    o[0][6] = __builtin_amdgcn_mfma_f32_16x16x32_bf16(paf0, x6, o[0][6], 0, 0, 0);
    o[1][6] = __builtin_amdgcn_mfma_f32_16x16x32_bf16(paf1, x6, o[1][6], 0, 0, 0);
    o[0][7] = __builtin_amdgcn_mfma_f32_16x16x32_bf16(paf0, x7, o[0][7], 0, 0, 0);
    o[1][7] = __builtin_amdgcn_mfma_f32_16x16x32_bf16(paf1, x7, o[1][7], 0, 0, 0);
    __builtin_amdgcn_s_setprio(0);
  }

  // ---- epilogue: ctx = O / lsum. lsum for q=16mt+(q4*4+r) lives on lane fm'=q4*4+r (q4'=0).
#pragma unroll
  for (int mt = 0; mt < 2; ++mt)
#pragma unroll
    for (int r = 0; r < 4; ++r) {
      float inv = 1.f / __shfl(lsumv[mt], q4 * 4 + r);
      int gq = b * LQ + qbase + mt * 16 + q4 * 4 + r;
#pragma unroll
      for (int dt = 0; dt < 8; ++dt)
        ctx[(size_t)gq * EDIM + h * DH + dt * 16 + fm] = f2bf(o[mt][dt][r] * inv);
    }
}

extern "C" void kernel_launch(void* const* d_in, const int* in_sizes, int n_in,
                              void* d_out, int out_size, void* d_ws, size_t ws_size,
                              hipStream_t stream) {
  const float* qIn = (const float*)d_in[0];
  const float* kvIn = (const float*)d_in[1];
  const unsigned char* mask = (const unsigned char*)d_in[2];
  const float* W_Q = (const float*)d_in[3];
  const float* W_K = (const float*)d_in[4];
  const float* W_V = (const float*)d_in[5];
  const float* W_fc = (const float*)d_in[6];
  float* out = (float*)d_out;

  uint8_t* ws = (uint8_t*)d_ws;
  const size_t MB = 1u << 20;
  u16* xq   = (u16*)(ws);
  u16* xkv  = (u16*)(ws + 16 * MB);
  u16* WqT  = (u16*)(ws + 32 * MB);
  u16* WkT  = (u16*)(ws + 34 * MB);
  u16* WvT  = (u16*)(ws + 36 * MB);
  u16* WfcT = (u16*)(ws + 38 * MB);
  u16* Qb   = (u16*)(ws + 40 * MB);
  u16* Kb   = (u16*)(ws + 56 * MB);
  u16* Vt   = (u16*)(ws + 72 * MB);
  u16* ctx  = (u16*)(ws + 88 * MB);
  unsigned char* flags = (unsigned char*)(ws + 104 * MB);

  prep_kernel<<<20480, 256, 0, stream>>>(qIn, kvIn, W_Q, W_K, W_V, W_fc,
                                         xq, xkv, WqT, WkT, WvT, WfcT);
  qkv_gemm<<<dim3(64, 8, 4), 256, 0, stream>>>(xq, xkv, WqT, WkT, WvT, Qb, Kb, Vt, mask, flags);
  attn_kernel<<<512, 256, 0, stream>>>(Qb, Kb, Vt, mask, flags, ctx);
  out_gemm<<<dim3(64, 8), 256, 0, stream>>>(ctx, WfcT, out);
}

// Round 6
// 812.597 us; speedup vs baseline: 1.0441x; 1.0172x over previous
//
#include <hip/hip_runtime.h>
#include <stdint.h>

#define LQ 2048
#define EDIM 1024
#define HN 8
#define DH 128
#define BATCH 4
#define SCALE_LOG2E 0.12753785051263942f  // (1/sqrt(128)) * log2(e) -- folded into Qb

typedef short bf16x8 __attribute__((ext_vector_type(8)));
typedef float f32x4 __attribute__((ext_vector_type(4)));
typedef unsigned short u16;
typedef unsigned short u16x4 __attribute__((ext_vector_type(4)));

__device__ __forceinline__ u16 f2bf(float f) {
  union { float f; uint32_t u; } c; c.f = f;
  uint32_t u = c.u;
  return (u16)((u + 0x7fffu + ((u >> 16) & 1u)) >> 16);
}

__device__ __forceinline__ void async16(const void* g, void* l) {
  __builtin_amdgcn_global_load_lds((const __attribute__((address_space(1))) void*)g,
                                   (__attribute__((address_space(3))) void*)l, 16, 0, 0);
}

// LDS byte address for inline-asm DS ops
__device__ __forceinline__ uint32_t lds_b(const u16* p) {
  return (uint32_t)(uintptr_t)(__attribute__((address_space(3))) const u16*)p;
}
// Issue-only 4x ds_read_b128 (NO drain). Outputs early-clobber; values valid only
// after a following counted lgkm wait. DS ops complete in order.
__device__ __forceinline__ void ldsr4_issue(bf16x8& d0, bf16x8& d1, bf16x8& d2, bf16x8& d3,
                                            uint32_t a0, uint32_t a1, uint32_t a2, uint32_t a3) {
  asm volatile("ds_read_b128 %0, %4\n\t"
               "ds_read_b128 %1, %5\n\t"
               "ds_read_b128 %2, %6\n\t"
               "ds_read_b128 %3, %7"
               : "=&v"(d0), "=&v"(d1), "=&v"(d2), "=&v"(d3)
               : "v"(a0), "v"(a1), "v"(a2), "v"(a3));
}
// Counted lgkm wait + scheduling fence. The sched_barrier is REQUIRED: hipcc
// hoists register-only MFMA past inline-asm waitcnt ("memory" doesn't order it).
template <int N>
__device__ __forceinline__ void lgkm_wait_sb() {
  asm volatile("s_waitcnt lgkmcnt(%0)" :: "n"(N) : "memory");
  __builtin_amdgcn_sched_barrier(0);
}
// v_cvt_pk_bf16_f32: two f32 -> packed 2xbf16 in one u32 (lo <- first arg).
__device__ __forceinline__ uint32_t cvtpk(float lo, float hi) {
  uint32_t r;
  asm("v_cvt_pk_bf16_f32 %0, %1, %2" : "=v"(r) : "v"(lo), "v"(hi));
  return r;
}
// P-redistribution on the VALU pipe. R3-validated builtin path (compiler inserts
// the DPP hazard wait-states raw asm omitted -- R2's correctness failure).
__device__ __forceinline__ void plane_swap(uint32_t& a, uint32_t& b) {
#if __has_builtin(__builtin_amdgcn_permlane32_swap) && __has_builtin(__builtin_amdgcn_permlane16_swap)
  auto r1 = __builtin_amdgcn_permlane32_swap(a, b, false, false);
  auto r2 = __builtin_amdgcn_permlane16_swap(r1[0], r1[1], false, false);
  a = r2[0];
  b = r2[1];
#else
  asm("s_nop 1\n\t"
      "v_permlane32_swap_b32 %0, %1\n\t"
      "s_nop 1\n\t"
      "v_permlane16_swap_b32 %0, %1\n\t"
      "s_nop 1"
      : "+v"(a), "+v"(b));
#endif
}
// DS-free butterfly sums (keep counted lgkm waits valid across softmax):
// permlaneN_swap(x,x) returns {out0,out1} with out0+out1 == x + x^N per lane
// (value-identical to the shfl_xor version -> bitwise-same lsum).
__device__ __forceinline__ float xorsum16(float x) {
#if __has_builtin(__builtin_amdgcn_permlane16_swap)
  union { float f; uint32_t u; } c; c.f = x;
  auto r = __builtin_amdgcn_permlane16_swap(c.u, c.u, false, false);
  union { uint32_t u; float f; } a, b; a.u = r[0]; b.u = r[1];
  return a.f + b.f;
#else
  return x + __shfl_xor(x, 16);   // correct fallback (slower: DS op)
#endif
}
__device__ __forceinline__ float xorsum32(float x) {
#if __has_builtin(__builtin_amdgcn_permlane32_swap)
  union { float f; uint32_t u; } c; c.f = x;
  auto r = __builtin_amdgcn_permlane32_swap(c.u, c.u, false, false);
  union { uint32_t u; float f; } a, b; a.u = r[0]; b.u = r[1];
  return a.f + b.f;
#else
  return x + __shfl_xor(x, 32);
#endif
}
// XCD-aware bijective tile swizzle for a 64x8 (or any 64-wide) tile grid:
// f = x + 64*y decomposes into radix-8 digits (d0,d1,d2); remap so d0 (the
// dispatch%8 = XCD digit under round-robin) selects a contiguous 8-wide x-stripe.
// XCD k then owns x in [8k,8k+8) across ALL y: A-stripe (2 MB) + B panel (2 MB)
// fit the 4 MB per-XCD L2. Pure bijection -> correctness-neutral regardless of
// the real dispatch->XCD mapping.
__device__ __forceinline__ void swz64(int& x, int& y) {
  const int f = x + 64 * y;
  x = (f & 7) * 8 + ((f >> 3) & 7);
  y = f >> 6;
}

// ---------------- fused prep: cvt inputs + transpose weights ----------------
__global__ __launch_bounds__(256) void prep_kernel(const float* __restrict__ qIn, const float* __restrict__ kvIn,
                                                   const float* __restrict__ w0, const float* __restrict__ w1,
                                                   const float* __restrict__ w2, const float* __restrict__ w3,
                                                   u16* __restrict__ oq, u16* __restrict__ okv,
                                                   u16* __restrict__ o0, u16* __restrict__ o1,
                                                   u16* __restrict__ o2, u16* __restrict__ o3) {
  __shared__ float tile[32][33];
  const int bid = blockIdx.x;
  const int t = threadIdx.x;
  if (bid < 16384) {
    const float* in = (bid >= 8192) ? kvIn : qIn;
    u16* out = (bid >= 8192) ? okv : oq;
    size_t i = (size_t)(bid & 8191) * 256 + t;
    float4 v = ((const float4*)in)[i];
    u16x4 o;
    o.x = f2bf(v.x); o.y = f2bf(v.y); o.z = f2bf(v.z); o.w = f2bf(v.w);
    ((u16x4*)out)[i] = o;
  } else {
    const int idx = bid - 16384;
    const int z = idx >> 10;
    const int rem = idx & 1023;
    const float* in; u16* out;
    switch (z) {
      case 0: in = w0; out = o0; break;
      case 1: in = w1; out = o1; break;
      case 2: in = w2; out = o2; break;
      default: in = w3; out = o3; break;
    }
    const int tx = t & 31, ty = t >> 5;
    const int x0 = (rem & 31) * 32;
    const int y0 = (rem >> 5) * 32;
#pragma unroll
    for (int j = 0; j < 32; j += 8)
      tile[ty + j][tx] = in[(size_t)(y0 + ty + j) * EDIM + x0 + tx];
    __syncthreads();
#pragma unroll
    for (int j = 0; j < 32; j += 8)
      out[(size_t)(x0 + ty + j) * EDIM + (y0 + tx)] = f2bf(tile[tx][ty + j]);
  }
}

// ---------------- BK=64 GEMM core (XOR-swizzled LDS, 128x128 tile) ----------------
struct GemmCore {
  template <typename EpiF>
  static __device__ __forceinline__ void run(const u16* __restrict__ A, const u16* __restrict__ Bt,
                                             int m0, int n0, u16* As, u16* Bs, EpiF epi) {
    const int tid = threadIdx.x;
    const int l = tid & 63;
    const int w = tid >> 6;
    const int wm = (w >> 1) * 64;
    const int wn = (w & 1) * 64;
    const int fm = l & 15;
    const int q4 = l >> 4;
    const int f7 = fm & 7;
    f32x4 acc[4][4] = {};
    for (int k0 = 0; k0 < EDIM; k0 += 64) {
      __syncthreads();
#pragma unroll
      for (int ii = 0; ii < 4; ++ii) {
        const int rloc = w * 32 + ii * 8 + (l >> 3);
        const int cs = (l & 7) ^ (rloc & 7);
        async16(A + (size_t)(m0 + rloc) * EDIM + k0 + cs * 8, &As[(w * 32 + ii * 8) * 64 + l * 8]);
        async16(Bt + (size_t)(n0 + rloc) * EDIM + k0 + cs * 8, &Bs[(w * 32 + ii * 8) * 64 + l * 8]);
      }
      __syncthreads();
#pragma unroll
      for (int ks = 0; ks < 2; ++ks) {
        const int coff = ((ks * 4 + q4) ^ f7) * 8;
        bf16x8 a[4], b[4];
#pragma unroll
        for (int i = 0; i < 4; ++i) a[i] = *(const bf16x8*)&As[(wm + i * 16 + fm) * 64 + coff];
#pragma unroll
        for (int j = 0; j < 4; ++j) b[j] = *(const bf16x8*)&Bs[(wn + j * 16 + fm) * 64 + coff];
#pragma unroll
        for (int i = 0; i < 4; ++i)
#pragma unroll
          for (int j = 0; j < 4; ++j)
            acc[i][j] = __builtin_amdgcn_mfma_f32_16x16x32_bf16(a[i], b[j], acc[i][j], 0, 0, 0);
      }
    }
    const int rr = q4 * 4;
#pragma unroll
    for (int i = 0; i < 4; ++i)
#pragma unroll
      for (int j = 0; j < 4; ++j)
#pragma unroll
        for (int r = 0; r < 4; ++r)
          epi(m0 + wm + i * 16 + rr + r, n0 + wn + j * 16 + fm, acc[i][j][r]);
  }
};

__global__ __launch_bounds__(256) void qkv_gemm(const u16* __restrict__ xq, const u16* __restrict__ xkv,
                                                const u16* __restrict__ WqT, const u16* __restrict__ WkT,
                                                const u16* __restrict__ WvT,
                                                u16* __restrict__ Qb, u16* __restrict__ Kb,
                                                u16* __restrict__ Vt) {
  __shared__ __align__(16) u16 As[128 * 64];
  __shared__ __align__(16) u16 Bs[128 * 64];
  const int z = blockIdx.z;
  int bx = blockIdx.x, by = blockIdx.y;
  swz64(bx, by);   // XCD-local A-stripe + B-panel (fits 4 MB L2)
  if (z == 0) {
    // scale*log2e folded into Q here: saves a v_mul per score in attn softmax
    GemmCore::run(xq, WqT, bx * 128, by * 128, As, Bs,
                  [&](int gm, int gn, float v) { Qb[(size_t)gm * EDIM + gn] = f2bf(v * SCALE_LOG2E); });
  } else if (z == 1) {
    GemmCore::run(xkv, WkT, bx * 128, by * 128, As, Bs,
                  [&](int gm, int gn, float v) { Kb[(size_t)gm * EDIM + gn] = f2bf(v); });
  } else {
    GemmCore::run(WvT, xkv, by * 128, bx * 128, As, Bs,
                  [&](int gm, int gn, float v) {
                    Vt[((size_t)(gn >> 11) * 1024 + gm) * 2048 + (gn & 2047)] = f2bf(v);
                  });
  }
}

__global__ __launch_bounds__(256) void out_gemm(const u16* __restrict__ ctx, const u16* __restrict__ WfcT,
                                                float* __restrict__ out) {
  __shared__ __align__(16) u16 As[128 * 64];
  __shared__ __align__(16) u16 Bs[128 * 64];
  int bx = blockIdx.x, by = blockIdx.y;
  swz64(bx, by);
  GemmCore::run(ctx, WfcT, bx * 128, by * 128, As, Bs,
                [&](int gm, int gn, float v) { out[(size_t)gm * EDIM + gn] = v; });
}

// ---------------- flash attention v8: self-scanned mask flags ----------------
// v7 -> v8: the mask tile scan moves from qkv_gemm (where its co-residency pinned
// qkv's 32KB-LDS structure) into attn as a per-wave rolling prefetch: attn is
// LDS-pipe-bound with ~50us of idle HBM headroom, so the 134 MB scan hides.
// Each wave scans ONLY its own 32 q-rows x 128 keys of tile t+1 (4 KB: 4x
// dwordx4/lane on even iters), OR-reduces in-lane, __any at use time -- no LDS,
// no cross-wave sync, finer flag granularity than the old per-128-row flags.
// Tile 0 is scanned in the prologue. qkv_gemm is now a pure GEMM (8-phase-ready).
__global__ __launch_bounds__(256, 2) void attn_kernel(const u16* __restrict__ Qb, const u16* __restrict__ Kb,
                                                      const u16* __restrict__ Vt,
                                                      const unsigned char* __restrict__ mask,
                                                      u16* __restrict__ ctx) {
  __shared__ __align__(16) u16 Ktile[2][64 * 128];   // [key][d] rows 256B = 16 chunks, XOR-swizzled
  __shared__ __align__(16) u16 Vtile[2][128 * 64];   // [d][key] rows 128B = 8 chunks, XOR-swizzled
  const int tid = threadIdx.x;
  const int l = tid & 63;
  const int w = tid >> 6;
  // panel-grouping swizzle: flat -> (qt, h, b) with each (b,h) panel's 16 q-tiles
  // on one XCD (assumes round-robin dispatch, id%8 = XCD; bijective either way).
  const int flat = blockIdx.x;          // 0..511
  const int xcd = flat & 7;
  const int idx = flat >> 3;            // 0..63
  const int panel = xcd * 4 + (idx >> 4);  // 0..31
  const int qt = idx & 15;
  const int h = panel & 7;
  const int b = panel >> 3;
  const int fm = l & 15;
  const int q4 = l >> 4;
  const int fk = q4 * 8;
  const int f7 = fm & 7;
  const int qbase = qt * 128 + w * 32;
  const int bh = b * HN + h;

  const u16* Kbh = Kb + (size_t)b * LQ * EDIM + h * DH;
  const u16* Vth = Vt + (size_t)bh * DH * LQ;
  const size_t mbase = (size_t)bh * (size_t)LQ * LQ;
  // per-wave mask scan: lane covers row qbase+(l>>1), 64B half (l&1)
  const unsigned char* mscan = mask + mbase + (size_t)(qbase + (l >> 1)) * LQ + (l & 1) * 64;

  // Q fragments (issued before DMA so vmcnt ordering keeps them oldest)
  bf16x8 qf[2][4];
#pragma unroll
  for (int mt = 0; mt < 2; ++mt)
#pragma unroll
    for (int ks = 0; ks < 4; ++ks)
      qf[mt][ks] = *(const bf16x8*)(Qb + (size_t)(b * LQ + qbase + mt * 16 + fm) * EDIM + h * DH + ks * 32 + fk);

  // prologue scan of mask tile 0 (keys 0..127 for this wave's 32 rows)
  uint32_t curAcc = 0, nxtAcc = 0;
#pragma unroll
  for (int j = 0; j < 4; ++j) {
    uint4 mv = *(const uint4*)(mscan + j * 16);
    curAcc |= mv.x | mv.y | mv.z | mv.w;
  }

  auto stageK = [&](int kt_, int buf) {
#pragma unroll
    for (int ii = 0; ii < 4; ++ii) {
      const int i = w * 4 + ii;
      const int row = i * 4 + (l >> 4);          // key row 0..63
      const int g = (l & 15) ^ (row & 7);        // global chunk fetched into slot l&15
      async16(Kbh + (size_t)(kt_ * 64 + row) * EDIM + g * 8, &Ktile[buf][i * 512 + l * 8]);
    }
  };
  auto stageV = [&](int kt_, int buf) {
#pragma unroll
    for (int ii = 0; ii < 4; ++ii) {
      const int i = w * 4 + ii;
      const int row = i * 8 + (l >> 3);          // d row 0..127
      const int g = (l & 7) ^ (row & 7);
      async16(Vth + (size_t)row * LQ + kt_ * 64 + g * 8, &Vtile[buf][i * 512 + l * 8]);
    }
  };

  stageK(0, 0);
  stageV(0, 0);

  f32x4 o[2][8] = {};
  float lsumv[2] = {0.f, 0.f};

  for (int it = 0; it < 32; ++it) {
    const int cur = it & 1;
    // one barrier: (a) drains own K/V(it) DMA (issued a full iter ago -> ~free),
    // (b) all waves done reading buffers [1-cur] from iter it-1.
    __syncthreads();
    if (it + 1 < 32) { stageK(it + 1, 1 - cur); stageV(it + 1, 1 - cur); }

    // rolling mask scan: on even iters, promote accumulated tile flag and start
    // loading tile (it/2)+1 (used 2 iters later; latency hides under this iter).
    if ((it & 1) == 0) {
      if (it > 0) curAcc = nxtAcc;
      nxtAcc = 0;
      const int tn = (it >> 1) + 1;
      if (tn < 16) {
        const unsigned char* ms = mscan + tn * 128;
#pragma unroll
        for (int j = 0; j < 4; ++j) {
          uint4 mv = *(const uint4*)(ms + j * 16);
          nxtAcc |= mv.x | mv.y | mv.z | mv.w;
        }
      }
    }
    const int hasMask = __any(curAcc != 0);

    const u16* KT = &Ktile[cur][0];
    const u16* VT = &Vtile[cur][0];

    // ---- St = K Q^T: 2-deep pipelined K-frag reads; ns=0 V reads issued in tail
    f32x4 st[4][2] = {};
    bf16x8 kf[2][4];
    bf16x8 v0, v1, v2, v3, v4, v5, v6, v7;   // ns=0 V frags (issued at ks=3)
    bf16x8 x0, x1, x2, x3, x4, x5, x6, x7;   // ns=1 V frags (issued after softmax-A)
    {
      const int slot = q4 ^ f7;                  // ks=0 chunk
      ldsr4_issue(kf[0][0], kf[0][1], kf[0][2], kf[0][3],
                  lds_b(KT + (0 * 16 + fm) * 128 + slot * 8),
                  lds_b(KT + (1 * 16 + fm) * 128 + slot * 8),
                  lds_b(KT + (2 * 16 + fm) * 128 + slot * 8),
                  lds_b(KT + (3 * 16 + fm) * 128 + slot * 8));
    }
#pragma unroll
    for (int ks = 0; ks < 3; ++ks) {
      const int c = ks & 1;
      const int slot = ((ks + 1) * 4 + q4) ^ f7;
      ldsr4_issue(kf[c ^ 1][0], kf[c ^ 1][1], kf[c ^ 1][2], kf[c ^ 1][3],
                  lds_b(KT + (0 * 16 + fm) * 128 + slot * 8),
                  lds_b(KT + (1 * 16 + fm) * 128 + slot * 8),
                  lds_b(KT + (2 * 16 + fm) * 128 + slot * 8),
                  lds_b(KT + (3 * 16 + fm) * 128 + slot * 8));
      lgkm_wait_sb<4>();                       // oldest 4 (slot ks) landed
      __builtin_amdgcn_s_setprio(1);
#pragma unroll
      for (int mt = 0; mt < 2; ++mt) {
        st[0][mt] = __builtin_amdgcn_mfma_f32_16x16x32_bf16(kf[c][0], qf[mt][ks], st[0][mt], 0, 0, 0);
        st[1][mt] = __builtin_amdgcn_mfma_f32_16x16x32_bf16(kf[c][1], qf[mt][ks], st[1][mt], 0, 0, 0);
        st[2][mt] = __builtin_amdgcn_mfma_f32_16x16x32_bf16(kf[c][2], qf[mt][ks], st[2][mt], 0, 0, 0);
        st[3][mt] = __builtin_amdgcn_mfma_f32_16x16x32_bf16(kf[c][3], qf[mt][ks], st[3][mt], 0, 0, 0);
      }
      __builtin_amdgcn_s_setprio(0);
    }
    {
      // ks = 3 tail: issue ns=0 V reads (8); lgkmcnt(8) proves the 4 K reads landed
      // while the V reads fly under the ks=3 MFMAs and softmax-A.
      const int vs0 = q4 ^ f7;
      ldsr4_issue(v0, v1, v2, v3,
                  lds_b(VT + (0 * 16 + fm) * 64 + vs0 * 8), lds_b(VT + (1 * 16 + fm) * 64 + vs0 * 8),
                  lds_b(VT + (2 * 16 + fm) * 64 + vs0 * 8), lds_b(VT + (3 * 16 + fm) * 64 + vs0 * 8));
      ldsr4_issue(v4, v5, v6, v7,
                  lds_b(VT + (4 * 16 + fm) * 64 + vs0 * 8), lds_b(VT + (5 * 16 + fm) * 64 + vs0 * 8),
                  lds_b(VT + (6 * 16 + fm) * 64 + vs0 * 8), lds_b(VT + (7 * 16 + fm) * 64 + vs0 * 8));
      lgkm_wait_sb<8>();
      __builtin_amdgcn_s_setprio(1);
#pragma unroll
      for (int mt = 0; mt < 2; ++mt) {
        st[0][mt] = __builtin_amdgcn_mfma_f32_16x16x32_bf16(kf[1][0], qf[mt][3], st[0][mt], 0, 0, 0);
        st[1][mt] = __builtin_amdgcn_mfma_f32_16x16x32_bf16(kf[1][1], qf[mt][3], st[1][mt], 0, 0, 0);
        st[2][mt] = __builtin_amdgcn_mfma_f32_16x16x32_bf16(kf[1][2], qf[mt][3], st[2][mt], 0, 0, 0);
        st[3][mt] = __builtin_amdgcn_mfma_f32_16x16x32_bf16(kf[1][3], qf[mt][3], st[3][mt], 0, 0, 0);
      }
      __builtin_amdgcn_s_setprio(0);
    }

    // ---- softmax phase A: kt 0,1 (scale pre-folded into Q; masked -> 0)
    uint32_t pk[2][4][2];
    float sA[2], sB[2];
    bf16x8 paf0, paf1;
#pragma unroll
    for (int mt = 0; mt < 2; ++mt) {
      float sum = 0.f;
      if (hasMask) {
        const unsigned char* mrow = mask + mbase + (size_t)(qbase + mt * 16 + fm) * LQ + it * 64 + q4 * 4;
#pragma unroll
        for (int kt = 0; kt < 2; ++kt) {
          const uint32_t mv = *(const uint32_t*)(mrow + kt * 16);
#pragma unroll
          for (int r = 0; r < 4; ++r) {
            float e = ((mv >> (8 * r)) & 0xffu) ? 0.f : exp2f(st[kt][mt][r]);
            st[kt][mt][r] = e;
            sum += e;
          }
        }
      } else {
#pragma unroll
        for (int kt = 0; kt < 2; ++kt)
#pragma unroll
          for (int r = 0; r < 4; ++r) {
            float e = exp2f(st[kt][mt][r]);
            st[kt][mt][r] = e;
            sum += e;
          }
      }
      sA[mt] = sum;
      pk[mt][0][0] = cvtpk(st[0][mt][0], st[0][mt][1]);
      pk[mt][0][1] = cvtpk(st[0][mt][2], st[0][mt][3]);
      pk[mt][1][0] = cvtpk(st[1][mt][0], st[1][mt][1]);
      pk[mt][1][1] = cvtpk(st[1][mt][2], st[1][mt][3]);
    }
    {
      union { uint32_t u[4]; bf16x8 v; } fb;
      uint32_t e0 = pk[0][0][0], f0 = pk[0][1][0];
      uint32_t e1 = pk[0][0][1], f1 = pk[0][1][1];
      plane_swap(e0, f0); plane_swap(e1, f1);
      fb.u[0] = e0; fb.u[1] = e1; fb.u[2] = f0; fb.u[3] = f1;
      paf0 = fb.v;
      uint32_t g0 = pk[1][0][0], h0 = pk[1][1][0];
      uint32_t g1 = pk[1][0][1], h1 = pk[1][1][1];
      plane_swap(g0, h0); plane_swap(g1, h1);
      fb.u[0] = g0; fb.u[1] = g1; fb.u[2] = h0; fb.u[3] = h1;
      paf1 = fb.v;
    }
    // issue ns=1 V reads now: land under PV ns=0's MFMAs
    {
      const int vs1 = (4 + q4) ^ f7;
      ldsr4_issue(x0, x1, x2, x3,
                  lds_b(VT + (0 * 16 + fm) * 64 + vs1 * 8), lds_b(VT + (1 * 16 + fm) * 64 + vs1 * 8),
                  lds_b(VT + (2 * 16 + fm) * 64 + vs1 * 8), lds_b(VT + (3 * 16 + fm) * 64 + vs1 * 8));
      ldsr4_issue(x4, x5, x6, x7,
                  lds_b(VT + (4 * 16 + fm) * 64 + vs1 * 8), lds_b(VT + (5 * 16 + fm) * 64 + vs1 * 8),
                  lds_b(VT + (6 * 16 + fm) * 64 + vs1 * 8), lds_b(VT + (7 * 16 + fm) * 64 + vs1 * 8));
    }
    lgkm_wait_sb<8>();   // v0..v7 (oldest 8) landed; x0..x7 still in flight
    __builtin_amdgcn_s_setprio(1);
    o[0][0] = __builtin_amdgcn_mfma_f32_16x16x32_bf16(paf0, v0, o[0][0], 0, 0, 0);
    o[1][0] = __builtin_amdgcn_mfma_f32_16x16x32_bf16(paf1, v0, o[1][0], 0, 0, 0);
    o[0][1] = __builtin_amdgcn_mfma_f32_16x16x32_bf16(paf0, v1, o[0][1], 0, 0, 0);
    o[1][1] = __builtin_amdgcn_mfma_f32_16x16x32_bf16(paf1, v1, o[1][1], 0, 0, 0);
    o[0][2] = __builtin_amdgcn_mfma_f32_16x16x32_bf16(paf0, v2, o[0][2], 0, 0, 0);
    o[1][2] = __builtin_amdgcn_mfma_f32_16x16x32_bf16(paf1, v2, o[1][2], 0, 0, 0);
    o[0][3] = __builtin_amdgcn_mfma_f32_16x16x32_bf16(paf0, v3, o[0][3], 0, 0, 0);
    o[1][3] = __builtin_amdgcn_mfma_f32_16x16x32_bf16(paf1, v3, o[1][3], 0, 0, 0);
    o[0][4] = __builtin_amdgcn_mfma_f32_16x16x32_bf16(paf0, v4, o[0][4], 0, 0, 0);
    o[1][4] = __builtin_amdgcn_mfma_f32_16x16x32_bf16(paf1, v4, o[1][4], 0, 0, 0);
    o[0][5] = __builtin_amdgcn_mfma_f32_16x16x32_bf16(paf0, v5, o[0][5], 0, 0, 0);
    o[1][5] = __builtin_amdgcn_mfma_f32_16x16x32_bf16(paf1, v5, o[1][5], 0, 0, 0);
    o[0][6] = __builtin_amdgcn_mfma_f32_16x16x32_bf16(paf0, v6, o[0][6], 0, 0, 0);
    o[1][6] = __builtin_amdgcn_mfma_f32_16x16x32_bf16(paf1, v6, o[1][6], 0, 0, 0);
    o[0][7] = __builtin_amdgcn_mfma_f32_16x16x32_bf16(paf0, v7, o[0][7], 0, 0, 0);
    o[1][7] = __builtin_amdgcn_mfma_f32_16x16x32_bf16(paf1, v7, o[1][7], 0, 0, 0);
    __builtin_amdgcn_s_setprio(0);

    // ---- softmax phase B: kt 2,3 + lsum reduction (VALU; interleaves with ns=0 MFMAs)
#pragma unroll
    for (int mt = 0; mt < 2; ++mt) {
      float sum = 0.f;
      if (hasMask) {
        const unsigned char* mrow = mask + mbase + (size_t)(qbase + mt * 16 + fm) * LQ + it * 64 + q4 * 4;
#pragma unroll
        for (int kt = 2; kt < 4; ++kt) {
          const uint32_t mv = *(const uint32_t*)(mrow + kt * 16);
#pragma unroll
          for (int r = 0; r < 4; ++r) {
            float e = ((mv >> (8 * r)) & 0xffu) ? 0.f : exp2f(st[kt][mt][r]);
            st[kt][mt][r] = e;
            sum += e;
          }
        }
      } else {
#pragma unroll
        for (int kt = 2; kt < 4; ++kt)
#pragma unroll
          for (int r = 0; r < 4; ++r) {
            float e = exp2f(st[kt][mt][r]);
            st[kt][mt][r] = e;
            sum += e;
          }
      }
      sB[mt] = sum;
      pk[mt][2][0] = cvtpk(st[2][mt][0], st[2][mt][1]);
      pk[mt][2][1] = cvtpk(st[2][mt][2], st[2][mt][3]);
      pk[mt][3][0] = cvtpk(st[3][mt][0], st[3][mt][1]);
      pk[mt][3][1] = cvtpk(st[3][mt][2], st[3][mt][3]);
    }
    {
      union { uint32_t u[4]; bf16x8 v; } fb;
      uint32_t e0 = pk[0][2][0], f0 = pk[0][3][0];
      uint32_t e1 = pk[0][2][1], f1 = pk[0][3][1];
      plane_swap(e0, f0); plane_swap(e1, f1);
      fb.u[0] = e0; fb.u[1] = e1; fb.u[2] = f0; fb.u[3] = f1;
      paf0 = fb.v;
      uint32_t g0 = pk[1][2][0], h0 = pk[1][3][0];
      uint32_t g1 = pk[1][2][1], h1 = pk[1][3][1];
      plane_swap(g0, h0); plane_swap(g1, h1);
      fb.u[0] = g0; fb.u[1] = g1; fb.u[2] = h0; fb.u[3] = h1;
      paf1 = fb.v;
    }
#pragma unroll
    for (int mt = 0; mt < 2; ++mt) {
      float t = sA[mt] + sB[mt];
      lsumv[mt] += xorsum32(xorsum16(t));   // value-identical to shfl_xor chain
    }

    lgkm_wait_sb<0>();   // x0..x7 landed
    __builtin_amdgcn_s_setprio(1);
    o[0][0] = __builtin_amdgcn_mfma_f32_16x16x32_bf16(paf0, x0, o[0][0], 0, 0, 0);
    o[1][0] = __builtin_amdgcn_mfma_f32_16x16x32_bf16(paf1, x0, o[1][0], 0, 0, 0);
    o[0][1] = __builtin_amdgcn_mfma_f32_16x16x32_bf16(paf0, x1, o[0][1], 0, 0, 0);
    o[1][1] = __builtin_amdgcn_mfma_f32_16x16x32_bf16(paf1, x1, o[1][1], 0, 0, 0);
    o[0][2] = __builtin_amdgcn_mfma_f32_16x16x32_bf16(paf0, x2, o[0][2], 0, 0, 0);
    o[1][2] = __builtin_amdgcn_mfma_f32_16x16x32_bf16(paf1, x2, o[1][2], 0, 0, 0);
    o[0][3] = __builtin_amdgcn_mfma_f32_16x16x32_bf16(paf0, x3, o[0][3], 0, 0, 0);
    o[1][3] = __builtin_amdgcn_mfma_f32_16x16x32_bf16(paf1, x3, o[1][3], 0, 0, 0);
    o[0][4] = __builtin_amdgcn_mfma_f32_16x16x32_bf16(paf0, x4, o[0][4], 0, 0, 0);
    o[1][4] = __builtin_amdgcn_mfma_f32_16x16x32_bf16(paf1, x4, o[1][4], 0, 0, 0);
    o[0][5] = __builtin_amdgcn_mfma_f32_16x16x32_bf16(paf0, x5, o[0][5], 0, 0, 0);
    o[1][5] = __builtin_amdgcn_mfma_f32_16x16x32_bf16(paf1, x5, o[1][5], 0, 0, 0);
    o[0][6] = __builtin_amdgcn_mfma_f32_16x16x32_bf16(paf0, x6, o[0][6], 0, 0, 0);
    o[1][6] = __builtin_amdgcn_mfma_f32_16x16x32_bf16(paf1, x6, o[1][6], 0, 0, 0);
    o[0][7] = __builtin_amdgcn_mfma_f32_16x16x32_bf16(paf0, x7, o[0][7], 0, 0, 0);
    o[1][7] = __builtin_amdgcn_mfma_f32_16x16x32_bf16(paf1, x7, o[1][7], 0, 0, 0);
    __builtin_amdgcn_s_setprio(0);
  }

  // ---- epilogue: ctx = O / lsum. lsum for q=16mt+(q4*4+r) lives on lane fm'=q4*4+r (q4'=0).
#pragma unroll
  for (int mt = 0; mt < 2; ++mt)
#pragma unroll
    for (int r = 0; r < 4; ++r) {
      float inv = 1.f / __shfl(lsumv[mt], q4 * 4 + r);
      int gq = b * LQ + qbase + mt * 16 + q4 * 4 + r;
#pragma unroll
      for (int dt = 0; dt < 8; ++dt)
        ctx[(size_t)gq * EDIM + h * DH + dt * 16 + fm] = f2bf(o[mt][dt][r] * inv);
    }
}

extern "C" void kernel_launch(void* const* d_in, const int* in_sizes, int n_in,
                              void* d_out, int out_size, void* d_ws, size_t ws_size,
                              hipStream_t stream) {
  const float* qIn = (const float*)d_in[0];
  const float* kvIn = (const float*)d_in[1];
  const unsigned char* mask = (const unsigned char*)d_in[2];
  const float* W_Q = (const float*)d_in[3];
  const float* W_K = (const float*)d_in[4];
  const float* W_V = (const float*)d_in[5];
  const float* W_fc = (const float*)d_in[6];
  float* out = (float*)d_out;

  uint8_t* ws = (uint8_t*)d_ws;
  const size_t MB = 1u << 20;
  u16* xq   = (u16*)(ws);
  u16* xkv  = (u16*)(ws + 16 * MB);
  u16* WqT  = (u16*)(ws + 32 * MB);
  u16* WkT  = (u16*)(ws + 34 * MB);
  u16* WvT  = (u16*)(ws + 36 * MB);
  u16* WfcT = (u16*)(ws + 38 * MB);
  u16* Qb   = (u16*)(ws + 40 * MB);
  u16* Kb   = (u16*)(ws + 56 * MB);
  u16* Vt   = (u16*)(ws + 72 * MB);
  u16* ctx  = (u16*)(ws + 88 * MB);

  prep_kernel<<<20480, 256, 0, stream>>>(qIn, kvIn, W_Q, W_K, W_V, W_fc,
                                         xq, xkv, WqT, WkT, WvT, WfcT);
  qkv_gemm<<<dim3(64, 8, 3), 256, 0, stream>>>(xq, xkv, WqT, WkT, WvT, Qb, Kb, Vt);
  attn_kernel<<<512, 256, 0, stream>>>(Qb, Kb, Vt, mask, ctx);
  out_gemm<<<dim3(64, 8), 256, 0, stream>>>(ctx, WfcT, out);
}